// Round 7
// baseline (127.218 us; speedup 1.0000x reference)
//
#include <hip/hip_runtime.h>

constexpr int Fdim = 2000;
constexpr int Wdim = 4000;
constexpr int Edim = 16;
constexpr int Hdim = 64;
constexpr int Bdim = 256;
constexpr int FTILE = 4;      // f-rows per block
constexpr int WCHUNKS = 2;    // w-chunks (blockIdx.y)
constexpr int NW = 8;         // CONSECUTIVE w's per thread (4 w-pairs)
constexpr int NQ = Hdim / 4;  // 16 h-quads
constexpr int W2 = Wdim / 2;  // 2000 w-pairs total
constexpr float kLog2e = 1.4426950408889634f;

typedef float v2f __attribute__((ext_vector_type(2)));

__device__ __forceinline__ float fast_exp2(float x) {
#if __has_builtin(__builtin_amdgcn_exp2f)
  return __builtin_amdgcn_exp2f(x);
#else
  return exp2f(x);
#endif
}
__device__ __forceinline__ float fast_rcp(float x) {
#if __has_builtin(__builtin_amdgcn_rcpf)
  return __builtin_amdgcn_rcpf(x);
#else
  return 1.0f / x;
#endif
}
__device__ __forceinline__ v2f v2s(float x) { v2f r; r.x = x; r.y = x; return r; }
__device__ __forceinline__ v2f v2fma(v2f a, v2f b, v2f c) {
  return __builtin_elementwise_fma(a, b, c);
}
__device__ __forceinline__ float4 f4_fma_s(float s, float4 a, float4 b) {
  return make_float4(fmaf(s, a.x, b.x), fmaf(s, a.y, b.y),
                     fmaf(s, a.z, b.z), fmaf(s, a.w, b.w));
}

// ---- DPP wave-64 sum (VALU pipe). Result valid in lane 63.
template <int CTRL>
__device__ __forceinline__ float dpp_part(float x) {
  return __int_as_float(
      __builtin_amdgcn_update_dpp(0, __float_as_int(x), CTRL, 0xF, 0xF, true));
}
__device__ __forceinline__ float wave64_sum(float x) {
  const float x0 = x;
  x += dpp_part<0x111>(x0);  // row_shr:1
  x += dpp_part<0x112>(x0);  // row_shr:2
  x += dpp_part<0x113>(x0);  // row_shr:3
  x += dpp_part<0x114>(x);   // row_shr:4
  x += dpp_part<0x118>(x);   // row_shr:8
  x += dpp_part<0x142>(x);   // row_bcast:15
  x += dpp_part<0x143>(x);   // row_bcast:31
  return x;                  // lane 63 holds the full sum
}

// --- prep (fused):
//   efp[f][h]      = exp2( (femb@Ww[:E] + b) * 2log2e )
//   ehp8[q][w2][8] = [k*2+t] = exp2( S * hid[4q+k][2*w2+t] )  (h-quad x w-pair)
//   wusum = sum(Wu);  mflag = mask layout (1 = byte bool, 0 = int32)
__global__ __launch_bounds__(256) void prep_kernel(
    const float* __restrict__ femb, const float* __restrict__ hemb,
    const float* __restrict__ Ww, const float* __restrict__ bw,
    const float* __restrict__ Wu, const unsigned char* __restrict__ mask,
    float* __restrict__ efp, float* __restrict__ ehp8,
    float* __restrict__ wusum, int* __restrict__ mflag) {
  constexpr float S = 2.0f * kLog2e;
  constexpr int NF = Fdim * Hdim;   // 128000 (500 blocks)
  constexpr int NH = NQ * W2;       // 32000  (125 blocks)
  int idx = blockIdx.x * 256 + threadIdx.x;
  if (idx < NF) {
    int f = idx >> 6, h = idx & 63;
    float acc = bw[h];
#pragma unroll
    for (int e = 0; e < Edim; ++e)
      acc = fmaf(femb[f * Edim + e], Ww[e * Hdim + h], acc);
    efp[idx] = fast_exp2(acc * S);
  } else if (idx < NF + NH) {
    int j = idx - NF;
    int q = j / W2, w2 = j - q * W2;
    float4 a0 = make_float4(0.f, 0.f, 0.f, 0.f);
    float4 a1 = make_float4(0.f, 0.f, 0.f, 0.f);
    const float* h0 = hemb + (size_t)(2 * w2) * Edim;
#pragma unroll
    for (int e = 0; e < Edim; ++e) {
      float4 wr = *(const float4*)(Ww + (Edim + e) * Hdim + 4 * q);  // uniform
      a0 = f4_fma_s(h0[e], wr, a0);
      a1 = f4_fma_s(h0[Edim + e], wr, a1);
    }
    float* o = ehp8 + (size_t)(q * W2 + w2) * 8;
    float4 o0 = make_float4(fast_exp2(a0.x * S), fast_exp2(a1.x * S),
                            fast_exp2(a0.y * S), fast_exp2(a1.y * S));
    float4 o1 = make_float4(fast_exp2(a0.z * S), fast_exp2(a1.z * S),
                            fast_exp2(a0.w * S), fast_exp2(a1.w * S));
    *(float4*)o = o0;
    *(float4*)(o + 4) = o1;
  } else if (idx < NF + NH + 64) {
    int l = idx - (NF + NH);        // wave 0 of last block
    float s = Wu[l];
#pragma unroll
    for (int o = 32; o > 0; o >>= 1) s += __shfl_down(s, o, 64);
    if (l == 0) *wusum = s;
  } else if (idx < NF + NH + 128) {
    // mask layout detect: bytes at i%4!=0 all zero <=> int32 layout
    int l = idx - (NF + NH + 64);   // wave 1 of last block
    int acc = 0;
    for (int i = l; i < 8192; i += 64)
      if ((i & 3) != 0) acc |= mask[i];
    unsigned long long b = __ballot(acc != 0);
    if (l == 0) *mflag = (b != 0ull) ? 1 : 0;
  }
}

// --- main: block = (f-tile, w-chunk). Thread owns 4 w-PAIRS (8 w's).
// Quad-h under one rcp, VOP3P-packed over the w-pair:
//   sum_k wu_k/d_k = [ (wu0*d1+wu1*d0)*d2*d3 + (wu2*d3+wu3*d2)*d0*d1 ] / prod d
//   d_k = 1 + efp[f][4q+k] * ehp[4q+k][w]
// efp/Wu enter via wave-uniform s_load; factor 2 folded into exp2 argument.
__global__ __launch_bounds__(256) void attn_ctx_kernel(
    const float* __restrict__ efp, const float* __restrict__ ehp8,
    const float* __restrict__ Wu, const float* __restrict__ wusum_p,
    const unsigned char* mask_b, const int* __restrict__ mflag,
    const float* __restrict__ hemb, float* __restrict__ part) {
  const int f0 = blockIdx.x * FTILE;
  const int chunk = blockIdx.y;
  const int tid = threadIdx.x;

  __shared__ float s_red[4][FTILE][20];  // [wave][fi][16 num + den@16]

  const int mbyte = *mflag;                // uniform (s_load)
  const float wls = (*wusum_p) * kLog2e;

  const int w2b = chunk * 1024 + tid * (NW / 2);  // first w-pair index
  const bool wok = (w2b < W2);
  const int w2c = wok ? w2b : (W2 - NW / 2);      // clamped
  const float* ebase = ehp8 + (size_t)w2c * 8;

  // sneg2[fi][j2]: packed over the w-pair
  v2f sneg2[FTILE][4];
#pragma unroll
  for (int fi = 0; fi < FTILE; ++fi)
#pragma unroll
    for (int j2 = 0; j2 < 4; ++j2) sneg2[fi][j2] = v2s(0.f);

  // ---- h-quad main loop: 8 dwordx4 (vector) + 5 s_load_dwordx4 (uniform)
#pragma unroll 2
  for (int q = 0; q < NQ; ++q) {
    float4 wuq = *(const float4*)(Wu + 4 * q);            // uniform -> SGPR
    float4 fq0 = *(const float4*)(efp + (f0 + 0) * Hdim + 4 * q);
    float4 fq1 = *(const float4*)(efp + (f0 + 1) * Hdim + 4 * q);
    float4 fq2 = *(const float4*)(efp + (f0 + 2) * Hdim + 4 * q);
    float4 fq3 = *(const float4*)(efp + (f0 + 3) * Hdim + 4 * q);
    const float4 fq[4] = {fq0, fq1, fq2, fq3};

    v2f e[4][4];  // [j2][k]
#pragma unroll
    for (int j2 = 0; j2 < 4; ++j2) {
      const float4* p =
          (const float4*)(ebase + (size_t)q * (W2 * 8) + j2 * 8);
      float4 A = p[0], B = p[1];
      e[j2][0].x = A.x; e[j2][0].y = A.y;
      e[j2][1].x = A.z; e[j2][1].y = A.w;
      e[j2][2].x = B.x; e[j2][2].y = B.y;
      e[j2][3].x = B.z; e[j2][3].y = B.w;
    }
#pragma unroll
    for (int j2 = 0; j2 < 4; ++j2)
#pragma unroll
      for (int fi = 0; fi < FTILE; ++fi) {
        v2f d0 = v2fma(e[j2][0], v2s(fq[fi].x), v2s(1.f));
        v2f d1 = v2fma(e[j2][1], v2s(fq[fi].y), v2s(1.f));
        v2f d2 = v2fma(e[j2][2], v2s(fq[fi].z), v2s(1.f));
        v2f d3 = v2fma(e[j2][3], v2s(fq[fi].w), v2s(1.f));
        v2f p01 = d0 * d1, p23 = d2 * d3;
        v2f n01 = v2fma(d0, v2s(wuq.y), d1 * v2s(wuq.x));
        v2f n23 = v2fma(d2, v2s(wuq.w), d3 * v2s(wuq.z));
        v2f num = v2fma(n01, p23, n23 * p01);
        v2f dd = p01 * p23;
        v2f r; r.x = fast_rcp(dd.x); r.y = fast_rcp(dd.y);
        sneg2[fi][j2] = v2fma(num, r, sneg2[fi][j2]);
      }
  }

  // ---- mask bits per (fi, w-pair), zeroed for invalid tails
  const int w0 = 2 * w2c;
  v2f mb[FTILE][4];
  if (mbyte) {
#pragma unroll
    for (int fi = 0; fi < FTILE; ++fi) {
      uint2 m = *(const uint2*)(mask_b + (size_t)(f0 + fi) * Wdim + w0);
      unsigned int lo = m.x, hi = m.y;
      mb[fi][0].x = (float)(lo & 1u);         mb[fi][0].y = (float)((lo >> 8) & 1u);
      mb[fi][1].x = (float)((lo >> 16) & 1u); mb[fi][1].y = (float)((lo >> 24) & 1u);
      mb[fi][2].x = (float)(hi & 1u);         mb[fi][2].y = (float)((hi >> 8) & 1u);
      mb[fi][3].x = (float)((hi >> 16) & 1u); mb[fi][3].y = (float)((hi >> 24) & 1u);
      if (!wok)
#pragma unroll
        for (int j2 = 0; j2 < 4; ++j2) mb[fi][j2] = v2s(0.f);
    }
  } else {
    const int* mask_i = (const int*)mask_b;
#pragma unroll
    for (int fi = 0; fi < FTILE; ++fi) {
      uint4 ma = *(const uint4*)(mask_i + (size_t)(f0 + fi) * Wdim + w0);
      uint4 mc = *(const uint4*)(mask_i + (size_t)(f0 + fi) * Wdim + w0 + 4);
      mb[fi][0].x = ma.x ? 1.f : 0.f; mb[fi][0].y = ma.y ? 1.f : 0.f;
      mb[fi][1].x = ma.z ? 1.f : 0.f; mb[fi][1].y = ma.w ? 1.f : 0.f;
      mb[fi][2].x = mc.x ? 1.f : 0.f; mb[fi][2].y = mc.y ? 1.f : 0.f;
      mb[fi][3].x = mc.z ? 1.f : 0.f; mb[fi][3].y = mc.w ? 1.f : 0.f;
      if (!wok)
#pragma unroll
        for (int j2 = 0; j2 < 4; ++j2) mb[fi][j2] = v2s(0.f);
    }
  }

  // ---- score + context accumulation (cacc packed over E)
  float den[FTILE] = {0.f, 0.f, 0.f, 0.f};
  v2f cacc2[FTILE][8];
#pragma unroll
  for (int fi = 0; fi < FTILE; ++fi)
#pragma unroll
    for (int t = 0; t < 8; ++t) cacc2[fi][t] = v2s(0.f);

  const float4* h4 = (const float4*)(hemb + (size_t)w0 * Edim);
#pragma unroll
  for (int j2 = 0; j2 < 4; ++j2) {
    float4 ha[4] = {h4[(2 * j2) * 4 + 0], h4[(2 * j2) * 4 + 1],
                    h4[(2 * j2) * 4 + 2], h4[(2 * j2) * 4 + 3]};
    float4 hb[4] = {h4[(2 * j2 + 1) * 4 + 0], h4[(2 * j2 + 1) * 4 + 1],
                    h4[(2 * j2 + 1) * 4 + 2], h4[(2 * j2 + 1) * 4 + 3]};
    v2f hv0[8], hv1[8];
#pragma unroll
    for (int t = 0; t < 4; ++t) {
      hv0[2 * t].x = ha[t].x;     hv0[2 * t].y = ha[t].y;
      hv0[2 * t + 1].x = ha[t].z; hv0[2 * t + 1].y = ha[t].w;
      hv1[2 * t].x = hb[t].x;     hv1[2 * t].y = hb[t].y;
      hv1[2 * t + 1].x = hb[t].z; hv1[2 * t + 1].y = hb[t].w;
    }
#pragma unroll
    for (int fi = 0; fi < FTILE; ++fi) {
      // factor 2 from 2*Wu folded here: arg = wls - 2*log2e*sneg'
      v2f arg = v2fma(sneg2[fi][j2], v2s(-2.0f * kLog2e), v2s(wls));
      float sc0 = fast_exp2(arg.x) * mb[fi][j2].x;
      float sc1 = fast_exp2(arg.y) * mb[fi][j2].y;
      den[fi] += sc0 + sc1;
#pragma unroll
      for (int t = 0; t < 8; ++t)
        cacc2[fi][t] =
            v2fma(v2s(sc0), hv0[t], v2fma(v2s(sc1), hv1[t], cacc2[fi][t]));
    }
  }

  // ---- DPP in-wave reduction, lane 63 -> LDS
  const int lane = tid & 63, wv = tid >> 6;
#pragma unroll
  for (int fi = 0; fi < FTILE; ++fi) {
    float d = wave64_sum(den[fi]);
    if (lane == 63) s_red[wv][fi][16] = d;
#pragma unroll
    for (int t = 0; t < 8; ++t) {
      float a = wave64_sum(cacc2[fi][t].x);
      float b = wave64_sum(cacc2[fi][t].y);
      if (lane == 63) {
        s_red[wv][fi][2 * t] = a;
        s_red[wv][fi][2 * t + 1] = b;
      }
    }
  }
  __syncthreads();
  if (tid < FTILE * 17) {
    int fi = tid / 17, k = tid % 17;
    float tot = s_red[0][fi][k] + s_red[1][fi][k] + s_red[2][fi][k] +
                s_red[3][fi][k];
    part[((f0 + fi) * WCHUNKS + chunk) * 17 + k] = tot;
  }
}

// --- finalize: ctx[f][e] = sum_c num / sum_c den ---------------------------
__global__ __launch_bounds__(256) void finalize_kernel(
    const float* __restrict__ part, float* __restrict__ ctx) {
  int idx = blockIdx.x * 256 + threadIdx.x;
  if (idx >= Fdim * Edim) return;
  int f = idx >> 4, e = idx & 15;
  const float* p = part + f * WCHUNKS * 17;
  float den = 0.f, num = 0.f;
#pragma unroll
  for (int c = 0; c < WCHUNKS; ++c) {
    den += p[c * 17 + 16];
    num += p[c * 17 + e];
  }
  ctx[idx] = num / den;
}

// --- out[b][e] = sum_f values[b][f] * ctx[f][e] ----------------------------
__global__ __launch_bounds__(256) void out_gemv_kernel(
    const float* __restrict__ values, const float* __restrict__ ctx,
    float* __restrict__ out) {
  const int b = blockIdx.x, tid = threadIdx.x;
  float acc[Edim];
#pragma unroll
  for (int e = 0; e < Edim; ++e) acc[e] = 0.f;
  for (int f = tid; f < Fdim; f += 256) {
    float v = values[b * Fdim + f];
    const float4* c4 = (const float4*)(ctx + f * Edim);
    float4 c0 = c4[0], c1 = c4[1], c2 = c4[2], c3 = c4[3];
    float cr[Edim] = {c0.x, c0.y, c0.z, c0.w, c1.x, c1.y, c1.z, c1.w,
                      c2.x, c2.y, c2.z, c2.w, c3.x, c3.y, c3.z, c3.w};
#pragma unroll
    for (int e = 0; e < Edim; ++e) acc[e] = fmaf(v, cr[e], acc[e]);
  }
  __shared__ float s_red[4][Edim];
  const int lane = tid & 63, wv = tid >> 6;
#pragma unroll
  for (int e = 0; e < Edim; ++e) {
    float a = wave64_sum(acc[e]);
    if (lane == 63) s_red[wv][e] = a;
  }
  __syncthreads();
  if (tid < Edim)
    out[b * Edim + tid] =
        s_red[0][tid] + s_red[1][tid] + s_red[2][tid] + s_red[3][tid];
}

extern "C" void kernel_launch(void* const* d_in, const int* in_sizes, int n_in,
                              void* d_out, int out_size, void* d_ws,
                              size_t ws_size, hipStream_t stream) {
  const float* values = (const float*)d_in[0];
  const float* femb   = (const float*)d_in[1];
  const float* hemb   = (const float*)d_in[2];
  const float* Ww     = (const float*)d_in[3];
  const float* bw     = (const float*)d_in[4];
  const float* Wu     = (const float*)d_in[5];
  const unsigned char* mask = (const unsigned char*)d_in[6];
  float* out = (float*)d_out;

  // workspace (floats): efp[F*H] | ehp8[H*W] | ctx[F*E] | wusum | mflag | part
  float* ws = (float*)d_ws;
  float* efp = ws;                                    // 128000
  float* ehp8 = efp + Fdim * Hdim;                    // 256000
  float* ctx = ehp8 + (size_t)Hdim * Wdim;            // 32000
  float* wusum = ctx + Fdim * Edim;                   // 1
  int* mflag = (int*)(wusum + 1);                     // 1
  float* part = (float*)(mflag + 1);                  // 2000*2*17 = 68000

  constexpr int NTOT = Fdim * Hdim + NQ * W2 + 128;   // 160128
  prep_kernel<<<dim3((NTOT + 255) / 256), dim3(256), 0, stream>>>(
      femb, hemb, Ww, bw, Wu, mask, efp, ehp8, wusum, mflag);

  attn_ctx_kernel<<<dim3(Fdim / FTILE, WCHUNKS), dim3(256), 0, stream>>>(
      efp, ehp8, Wu, wusum, mask, mflag, hemb, part);

  finalize_kernel<<<dim3((Fdim * Edim + 255) / 256), dim3(256), 0, stream>>>(
      part, ctx);

  out_gemv_kernel<<<dim3(Bdim), dim3(256), 0, stream>>>(values, ctx, out);
}

// Round 8
// 97.439 us; speedup vs baseline: 1.3056x; 1.3056x over previous
//
#include <hip/hip_runtime.h>

constexpr int Fdim = 2000;
constexpr int Wdim = 4000;
constexpr int Edim = 16;
constexpr int Hdim = 64;
constexpr int Bdim = 256;
constexpr int FTILE = 4;
constexpr float kLog2e = 1.4426950408889634f;

// ---- MFMA-path padded dims
constexpr int Mp = 2048;   // padded F
constexpr int Np = 4096;   // padded W
constexpr int Kp = 320;    // 5 powers x 64 h

typedef float v2f __attribute__((ext_vector_type(2)));
typedef _Float16 f16x8 __attribute__((ext_vector_type(8)));
typedef float f32x4 __attribute__((ext_vector_type(4)));

__device__ __forceinline__ float fast_exp2(float x) {
#if __has_builtin(__builtin_amdgcn_exp2f)
  return __builtin_amdgcn_exp2f(x);
#else
  return exp2f(x);
#endif
}
__device__ __forceinline__ float fast_rcp(float x) {
#if __has_builtin(__builtin_amdgcn_rcpf)
  return __builtin_amdgcn_rcpf(x);
#else
  return 1.0f / x;
#endif
}
__device__ __forceinline__ v2f v2s(float x) { v2f r; r.x = x; r.y = x; return r; }
__device__ __forceinline__ v2f v2fma(v2f a, v2f b, v2f c) {
  return __builtin_elementwise_fma(a, b, c);
}
__device__ __forceinline__ float4 f4_fma_s(float s, float4 a, float4 b) {
  return make_float4(fmaf(s, a.x, b.x), fmaf(s, a.y, b.y),
                     fmaf(s, a.z, b.z), fmaf(s, a.w, b.w));
}
__device__ __forceinline__ float dev_tanh(float x) {
  // tanh(x) = 1 - 2/(1+e^{2x}), e^{2x} = exp2(2*log2e*x)
  return 1.0f - 2.0f * fast_rcp(fast_exp2(2.0f * kLog2e * x) + 1.0f);
}

// ---- DPP wave-64 sum (VALU pipe). Result valid in lane 63.
template <int CTRL>
__device__ __forceinline__ float dpp_part(float x) {
  return __int_as_float(
      __builtin_amdgcn_update_dpp(0, __float_as_int(x), CTRL, 0xF, 0xF, true));
}
__device__ __forceinline__ float wave64_sum(float x) {
  const float x0 = x;
  x += dpp_part<0x111>(x0);  // row_shr:1
  x += dpp_part<0x112>(x0);  // row_shr:2
  x += dpp_part<0x113>(x0);  // row_shr:3
  x += dpp_part<0x114>(x);   // row_shr:4
  x += dpp_part<0x118>(x);   // row_shr:8
  x += dpp_part<0x142>(x);   // row_bcast:15
  x += dpp_part<0x143>(x);   // row_bcast:31
  return x;                  // lane 63 holds the full sum
}

// ============================================================================
// ===========================  NEW MFMA PATH  ================================
// ============================================================================

// prep2: build fp16 GEMM operands + padded hemb + mask-layout flag.
//   A[f][j*64+h] = tanh(s[f,h])^j, j=0..4   (s = femb@Ww[:E], NO bias)
//   B[w][j*64+h] = Wu[h]*{q, 1-q^2, -q+q^3, q^2-q^4, -q^3}, q=tanh(hid+b)
//   pads zero-filled; hembp[w][e] padded copy of hemb.
__global__ __launch_bounds__(256) void prep2_kernel(
    const float* __restrict__ femb, const float* __restrict__ hemb,
    const float* __restrict__ Ww, const float* __restrict__ bw,
    const float* __restrict__ Wu, const unsigned char* __restrict__ mask,
    _Float16* __restrict__ A, _Float16* __restrict__ B,
    float* __restrict__ hembp, int* __restrict__ mflag) {
  constexpr int PA = Fdim * Hdim;                 // 128000
  constexpr int PB = PA + Wdim * Hdim;            // 384000
  constexpr int PAZ = PB + (Mp - Fdim) * Kp / 2;  // 391680 (u32 zero-fill A)
  constexpr int PBZ = PAZ + (Np - Wdim) * Kp / 2; // 407040 (u32 zero-fill B)
  constexpr int PH = PBZ + Np * Edim / 4;         // 423424 (float4 hembp)
  constexpr int PM = PH + 64;                     // 423488
  int idx = blockIdx.x * 256 + threadIdx.x;
  if (idx < PA) {
    int f = idx >> 6, h = idx & 63;
    float s = 0.f;
#pragma unroll
    for (int e = 0; e < Edim; ++e)
      s = fmaf(femb[f * Edim + e], Ww[e * Hdim + h], s);
    float p = dev_tanh(s);
    _Float16* a = A + (size_t)f * Kp + h;
    float pj = 1.0f;
#pragma unroll
    for (int j = 0; j < 5; ++j) {
      a[j * 64] = (_Float16)pj;
      pj *= p;
    }
  } else if (idx < PB) {
    int jj = idx - PA;
    int w = jj >> 6, h = jj & 63;
    float t = bw[h];
#pragma unroll
    for (int e = 0; e < Edim; ++e)
      t = fmaf(hemb[w * Edim + e], Ww[(Edim + e) * Hdim + h], t);
    float q = dev_tanh(t);
    float wu = Wu[h];
    float q2 = q * q, q3 = q2 * q;
    _Float16* b = B + (size_t)w * Kp + h;
    b[0 * 64] = (_Float16)(wu * q);
    b[1 * 64] = (_Float16)(wu * (1.0f - q2));
    b[2 * 64] = (_Float16)(wu * (q3 - q));
    b[3 * 64] = (_Float16)(wu * (q2 - q2 * q2));
    b[4 * 64] = (_Float16)(-wu * q3);
  } else if (idx < PAZ) {
    int j = idx - PB;
    ((unsigned int*)(A + (size_t)Fdim * Kp))[j] = 0u;
  } else if (idx < PBZ) {
    int j = idx - PAZ;
    ((unsigned int*)(B + (size_t)Wdim * Kp))[j] = 0u;
  } else if (idx < PH) {
    int j = idx - PBZ;                 // float4 index into hembp
    int w = j >> 2, qq = j & 3;
    float4 v = make_float4(0.f, 0.f, 0.f, 0.f);
    if (w < Wdim) v = ((const float4*)hemb)[w * 4 + qq];
    ((float4*)hembp)[j] = v;
  } else if (idx < PM) {
    // mask layout detect: bytes at i%4!=0 all zero <=> int32 layout
    int l = idx - PH;
    int acc = 0;
    for (int i = l; i < 8192; i += 64)
      if ((i & 3) != 0) acc |= mask[i];
    unsigned long long bl = __ballot(acc != 0);
    if (l == 0) *mflag = (bl != 0ull) ? 1 : 0;
  }
}

// score_gemm: sc[f][w] = mask ? exp(A@B^T) : 0, fp16 out, padded region -> 0.
// 256 threads = 4 waves (2x2), wave computes 64x64 via 4x4 frags of 16x16x32.
// A-frag: lane row=l&15, k=(l>>4)*8.. ; B-frag: col=l&15 (B stored [N][K]).
// C/D: col=lane&15, row=(lane>>4)*4+r  [guide §3, m89-verified].
__global__ __launch_bounds__(256) void score_gemm_kernel(
    const _Float16* __restrict__ A, const _Float16* __restrict__ B,
    const unsigned char* __restrict__ mask_b, const int* __restrict__ mflag,
    _Float16* __restrict__ sc) {
  const int tid = threadIdx.x;
  const int wid = tid >> 6, lane = tid & 63;
  const int wr = wid >> 1, wc = wid & 1;
  const int mwave = blockIdx.y * 128 + wr * 64;
  const int nwave = blockIdx.x * 128 + wc * 64;
  const int lrow = lane & 15, lk8 = (lane >> 4) * 8;

  f32x4 acc[4][4];
#pragma unroll
  for (int i = 0; i < 4; ++i)
#pragma unroll
    for (int j = 0; j < 4; ++j) acc[i][j] = (f32x4){0.f, 0.f, 0.f, 0.f};

  const _Float16* Ab = A + (size_t)(mwave + lrow) * Kp + lk8;
  const _Float16* Bb = B + (size_t)(nwave + lrow) * Kp + lk8;
#pragma unroll 2
  for (int ks = 0; ks < Kp / 32; ++ks) {
    f16x8 a[4], b[4];
#pragma unroll
    for (int i = 0; i < 4; ++i) {
      a[i] = *(const f16x8*)(Ab + (size_t)i * 16 * Kp + ks * 32);
      b[i] = *(const f16x8*)(Bb + (size_t)i * 16 * Kp + ks * 32);
    }
#pragma unroll
    for (int mi = 0; mi < 4; ++mi)
#pragma unroll
      for (int nj = 0; nj < 4; ++nj)
        acc[mi][nj] = __builtin_amdgcn_mfma_f32_16x16x32_f16(
            a[mi], b[nj], acc[mi][nj], 0, 0, 0);
  }

  const int mbyte = *mflag;
  const int* mask_i = (const int*)mask_b;
  const int rbase = (lane >> 4) * 4;
#pragma unroll
  for (int mi = 0; mi < 4; ++mi) {
#pragma unroll
    for (int nj = 0; nj < 4; ++nj) {
      const int w = nwave + nj * 16 + lrow;
      const bool wv = (w < Wdim);
#pragma unroll
      for (int r = 0; r < 4; ++r) {
        const int f = mwave + mi * 16 + rbase + r;
        float m = 0.f;
        if (wv && f < Fdim)
          m = mbyte ? (float)(mask_b[(size_t)f * Wdim + w] != 0)
                    : (float)(mask_i[(size_t)f * Wdim + w] != 0);
        float v = (m != 0.f) ? fast_exp2(acc[mi][nj][r] * kLog2e) : 0.f;
        sc[(size_t)f * Np + w] = (_Float16)v;
      }
    }
  }
}

// ctx2: den[f] = sum_w sc, num[f][e] = sum_w sc*hemb[w][e]; DPP reduce.
// block = (f-tile of 4, half of padded W). sc pad region is exact zeros.
__global__ __launch_bounds__(256) void ctx2_kernel(
    const _Float16* __restrict__ sc, const float* __restrict__ hembp,
    float* __restrict__ part) {
  const int f0 = blockIdx.x * FTILE;
  const int chunk = blockIdx.y;                 // 0,1
  const int tid = threadIdx.x;
  const int w0 = chunk * 2048 + tid * 8;

  __shared__ float s_red[4][FTILE][20];

  f16x8 scv[FTILE];
#pragma unroll
  for (int fi = 0; fi < FTILE; ++fi)
    scv[fi] = *(const f16x8*)(sc + (size_t)(f0 + fi) * Np + w0);

  float den[FTILE] = {0.f, 0.f, 0.f, 0.f};
  v2f cacc[FTILE][8];
#pragma unroll
  for (int fi = 0; fi < FTILE; ++fi)
#pragma unroll
    for (int t = 0; t < 8; ++t) cacc[fi][t] = v2s(0.f);

#pragma unroll
  for (int jw = 0; jw < 8; ++jw) {
    const float4* h4 = (const float4*)(hembp + (size_t)(w0 + jw) * Edim);
    float4 h0 = h4[0], h1 = h4[1], h2 = h4[2], h3 = h4[3];
    v2f hv[8];
    hv[0].x = h0.x; hv[0].y = h0.y; hv[1].x = h0.z; hv[1].y = h0.w;
    hv[2].x = h1.x; hv[2].y = h1.y; hv[3].x = h1.z; hv[3].y = h1.w;
    hv[4].x = h2.x; hv[4].y = h2.y; hv[5].x = h2.z; hv[5].y = h2.w;
    hv[6].x = h3.x; hv[6].y = h3.y; hv[7].x = h3.z; hv[7].y = h3.w;
#pragma unroll
    for (int fi = 0; fi < FTILE; ++fi) {
      float s = (float)scv[fi][jw];
      den[fi] += s;
#pragma unroll
      for (int t = 0; t < 8; ++t) cacc[fi][t] = v2fma(v2s(s), hv[t], cacc[fi][t]);
    }
  }

  const int lane = tid & 63, wv = tid >> 6;
#pragma unroll
  for (int fi = 0; fi < FTILE; ++fi) {
    float d = wave64_sum(den[fi]);
    if (lane == 63) s_red[wv][fi][16] = d;
#pragma unroll
    for (int t = 0; t < 8; ++t) {
      float a = wave64_sum(cacc[fi][t].x);
      float b = wave64_sum(cacc[fi][t].y);
      if (lane == 63) {
        s_red[wv][fi][2 * t] = a;
        s_red[wv][fi][2 * t + 1] = b;
      }
    }
  }
  __syncthreads();
  if (tid < FTILE * 17) {
    int fi = tid / 17, k = tid % 17;
    float tot = s_red[0][fi][k] + s_red[1][fi][k] + s_red[2][fi][k] +
                s_red[3][fi][k];
    part[((size_t)(f0 + fi) * 2 + chunk) * 17 + k] = tot;
  }
}

__global__ __launch_bounds__(256) void finalize2_kernel(
    const float* __restrict__ part, float* __restrict__ ctx) {
  int idx = blockIdx.x * 256 + threadIdx.x;
  if (idx >= Fdim * Edim) return;
  int f = idx >> 4, e = idx & 15;
  const float* p = part + (size_t)f * 2 * 17;
  float den = p[16] + p[17 + 16];
  float num = p[e] + p[17 + e];
  ctx[idx] = num / den;
}

// ============================================================================
// =====================  FALLBACK PATH (R5, proven)  =========================
// ============================================================================
constexpr int FB_WCHUNKS = 4;
constexpr int FB_WTILE = 1024;
constexpr int FB_NW = 4;
constexpr int W2 = Wdim / 2;

__global__ void detect_mask_kernel(const unsigned char* __restrict__ mask,
                                   int* __restrict__ flag) {
  __shared__ int any;
  if (threadIdx.x == 0) any = 0;
  __syncthreads();
  int acc = 0;
  for (int i = threadIdx.x; i < 8192; i += 256)
    if ((i & 3) != 0) acc |= mask[i];
  if (acc) atomicOr(&any, 1);
  __syncthreads();
  if (threadIdx.x == 0) *flag = (any != 0) ? 1 : 0;
}

__global__ __launch_bounds__(256) void prep_fb_kernel(
    const float* __restrict__ femb, const float* __restrict__ hemb,
    const float* __restrict__ Ww, const float* __restrict__ bw,
    const float* __restrict__ Wu,
    float* __restrict__ efp, float* __restrict__ ehp2,
    float* __restrict__ wusum) {
  constexpr float S = 2.0f * kLog2e;
  constexpr int NF = Fdim * Hdim;
  constexpr int NH2 = (Hdim / 2) * Wdim;
  int idx = blockIdx.x * 256 + threadIdx.x;
  if (idx < NF) {
    int f = idx >> 6, h = idx & 63;
    float acc = bw[h];
#pragma unroll
    for (int e = 0; e < Edim; ++e)
      acc = fmaf(femb[f * Edim + e], Ww[e * Hdim + h], acc);
    efp[idx] = fast_exp2(acc * S);
  } else if (idx < NF + NH2) {
    int j = idx - NF;
    int h2 = j / Wdim, w = j - h2 * Wdim;
    float a0 = 0.f, a1 = 0.f;
#pragma unroll
    for (int e = 0; e < Edim; ++e) {
      float he = hemb[w * Edim + e];
      a0 = fmaf(he, Ww[(Edim + e) * Hdim + 2 * h2 + 0], a0);
      a1 = fmaf(he, Ww[(Edim + e) * Hdim + 2 * h2 + 1], a1);
    }
    ((float2*)ehp2)[h2 * Wdim + w] =
        make_float2(fast_exp2(a0 * S), fast_exp2(a1 * S));
  } else if (idx < NF + NH2 + 64) {
    int l = idx - (NF + NH2);
    float s = Wu[l];
#pragma unroll
    for (int o = 32; o > 0; o >>= 1) s += __shfl_down(s, o, 64);
    if (l == 0) *wusum = s;
  }
}

__global__ __launch_bounds__(256) void attn_fb_kernel(
    const float* __restrict__ efp, const float* __restrict__ ehp2,
    const float* __restrict__ Wu, const float* __restrict__ wusum_p,
    const unsigned char* mask_b, const int* __restrict__ mflag,
    const float* __restrict__ hemb, float* __restrict__ part) {
  const int f0 = blockIdx.x * FTILE;
  const int chunk = blockIdx.y;
  const int tid = threadIdx.x;

  __shared__ float4 s_fpA[Hdim / 2];
  __shared__ float4 s_fpB[Hdim / 2];
  __shared__ float2 s_wu2[Hdim / 2];
  __shared__ float s_red[4][FTILE][20];

  if (tid < Hdim / 2) {
    const int h2 = tid;
    float2 p0 = *(const float2*)(efp + (f0 + 0) * Hdim + 2 * h2);
    float2 p1 = *(const float2*)(efp + (f0 + 1) * Hdim + 2 * h2);
    float2 p2 = *(const float2*)(efp + (f0 + 2) * Hdim + 2 * h2);
    float2 p3 = *(const float2*)(efp + (f0 + 3) * Hdim + 2 * h2);
    s_fpA[h2] = make_float4(p0.x, p1.x, p2.x, p3.x);
    s_fpB[h2] = make_float4(p0.y, p1.y, p2.y, p3.y);
    float2 wu = *(const float2*)(Wu + 2 * h2);
    s_wu2[h2] = make_float2(2.0f * wu.x, 2.0f * wu.y);
  }
  __syncthreads();

  const int mbyte = *mflag;
  const float wls = (*wusum_p) * kLog2e;

  const int w0 = chunk * FB_WTILE + tid * FB_NW;
  const bool wok = (w0 < Wdim);
  const int wcl = wok ? w0 : (Wdim - FB_NW);

  float sneg[FTILE][FB_NW];
#pragma unroll
  for (int fi = 0; fi < FTILE; ++fi)
#pragma unroll
    for (int j = 0; j < FB_NW; ++j) sneg[fi][j] = 0.f;

#pragma unroll 4
  for (int h2 = 0; h2 < Hdim / 2; ++h2) {
    const float* row = ehp2 + ((size_t)h2 * Wdim + wcl) * 2;
    float4 ea = *(const float4*)(row);
    float4 eb = *(const float4*)(row + 4);
    float4 fpA = s_fpA[h2];
    float4 fpB = s_fpB[h2];
    float2 wu = s_wu2[h2];
    float e0[FB_NW] = {ea.x, ea.z, eb.x, eb.z};
    float e1[FB_NW] = {ea.y, ea.w, eb.y, eb.w};
    float fA[4] = {fpA.x, fpA.y, fpA.z, fpA.w};
    float fB[4] = {fpB.x, fpB.y, fpB.z, fpB.w};
#pragma unroll
    for (int j = 0; j < FB_NW; ++j)
#pragma unroll
      for (int fi = 0; fi < FTILE; ++fi) {
        float d0 = fmaf(fA[fi], e0[j], 1.0f);
        float d1 = fmaf(fB[fi], e1[j], 1.0f);
        float num = fmaf(wu.y, d0, wu.x * d1);
        sneg[fi][j] = fmaf(num, fast_rcp(d0 * d1), sneg[fi][j]);
      }
  }

  float mbit[FTILE][FB_NW];
  if (mbyte) {
#pragma unroll
    for (int fi = 0; fi < FTILE; ++fi) {
      unsigned int m =
          *(const unsigned int*)(mask_b + (size_t)(f0 + fi) * Wdim + wcl);
#pragma unroll
      for (int j = 0; j < FB_NW; ++j)
        mbit[fi][j] = wok ? (float)((m >> (8 * j)) & 1u) : 0.f;
    }
  } else {
    const int* mask_i = (const int*)mask_b;
#pragma unroll
    for (int fi = 0; fi < FTILE; ++fi) {
      uint4 m4 = *(const uint4*)(mask_i + (size_t)(f0 + fi) * Wdim + wcl);
      unsigned int mm[FB_NW] = {m4.x, m4.y, m4.z, m4.w};
#pragma unroll
      for (int j = 0; j < FB_NW; ++j)
        mbit[fi][j] = (wok && mm[j]) ? 1.f : 0.f;
    }
  }

  float den[FTILE] = {0.f, 0.f, 0.f, 0.f};
  float4 cacc[FTILE][4];
#pragma unroll
  for (int fi = 0; fi < FTILE; ++fi)
#pragma unroll
    for (int q = 0; q < 4; ++q) cacc[fi][q] = make_float4(0.f, 0.f, 0.f, 0.f);

  const float4* h4 = (const float4*)(hemb + (size_t)wcl * Edim);
#pragma unroll
  for (int j = 0; j < FB_NW; ++j) {
    float4 hr0 = h4[j * 4 + 0], hr1 = h4[j * 4 + 1];
    float4 hr2 = h4[j * 4 + 2], hr3 = h4[j * 4 + 3];
#pragma unroll
    for (int fi = 0; fi < FTILE; ++fi) {
      float sc = fast_exp2(fmaf(sneg[fi][j], -kLog2e, wls)) * mbit[fi][j];
      den[fi] += sc;
      cacc[fi][0] = f4_fma_s(sc, hr0, cacc[fi][0]);
      cacc[fi][1] = f4_fma_s(sc, hr1, cacc[fi][1]);
      cacc[fi][2] = f4_fma_s(sc, hr2, cacc[fi][2]);
      cacc[fi][3] = f4_fma_s(sc, hr3, cacc[fi][3]);
    }
  }

  const int lane = tid & 63, wv = tid >> 6;
#pragma unroll
  for (int fi = 0; fi < FTILE; ++fi) {
    float d = wave64_sum(den[fi]);
    if (lane == 63) s_red[wv][fi][16] = d;
#pragma unroll
    for (int q = 0; q < 4; ++q) {
      float cx = wave64_sum(cacc[fi][q].x);
      float cy = wave64_sum(cacc[fi][q].y);
      float cz = wave64_sum(cacc[fi][q].z);
      float cw = wave64_sum(cacc[fi][q].w);
      if (lane == 63) {
        s_red[wv][fi][4 * q + 0] = cx;
        s_red[wv][fi][4 * q + 1] = cy;
        s_red[wv][fi][4 * q + 2] = cz;
        s_red[wv][fi][4 * q + 3] = cw;
      }
    }
  }
  __syncthreads();
  if (tid < FTILE * 17) {
    int fi = tid / 17, k = tid % 17;
    float tot = s_red[0][fi][k] + s_red[1][fi][k] + s_red[2][fi][k] +
                s_red[3][fi][k];
    part[((f0 + fi) * FB_WCHUNKS + chunk) * 17 + k] = tot;
  }
}

__global__ __launch_bounds__(256) void finalize_fb_kernel(
    const float* __restrict__ part, float* __restrict__ ctx) {
  int idx = blockIdx.x * 256 + threadIdx.x;
  if (idx >= Fdim * Edim) return;
  int f = idx >> 4, e = idx & 15;
  const float* p = part + f * FB_WCHUNKS * 17;
  float den = 0.f, num = 0.f;
#pragma unroll
  for (int c = 0; c < FB_WCHUNKS; ++c) {
    den += p[c * 17 + 16];
    num += p[c * 17 + e];
  }
  ctx[idx] = num / den;
}

// --- shared: out[b][e] = sum_f values[b][f] * ctx[f][e] ---------------------
__global__ __launch_bounds__(256) void out_gemv_kernel(
    const float* __restrict__ values, const float* __restrict__ ctx,
    float* __restrict__ out) {
  const int b = blockIdx.x, tid = threadIdx.x;
  float acc[Edim];
#pragma unroll
  for (int e = 0; e < Edim; ++e) acc[e] = 0.f;
  for (int f = tid; f < Fdim; f += 256) {
    float v = values[b * Fdim + f];
    const float4* c4 = (const float4*)(ctx + f * Edim);
    float4 c0 = c4[0], c1 = c4[1], c2 = c4[2], c3 = c4[3];
    float cr[Edim] = {c0.x, c0.y, c0.z, c0.w, c1.x, c1.y, c1.z, c1.w,
                      c2.x, c2.y, c2.z, c2.w, c3.x, c3.y, c3.z, c3.w};
#pragma unroll
    for (int e = 0; e < Edim; ++e) acc[e] = fmaf(v, cr[e], acc[e]);
  }
  __shared__ float s_red[4][Edim];
  const int lane = tid & 63, wv = tid >> 6;
#pragma unroll
  for (int e = 0; e < Edim; ++e) {
    float a = wave64_sum(acc[e]);
    if (lane == 63) s_red[wv][e] = a;
  }
  __syncthreads();
  if (tid < Edim)
    out[b * Edim + tid] =
        s_red[0][tid] + s_red[1][tid] + s_red[2][tid] + s_red[3][tid];
}

extern "C" void kernel_launch(void* const* d_in, const int* in_sizes, int n_in,
                              void* d_out, int out_size, void* d_ws,
                              size_t ws_size, hipStream_t stream) {
  const float* values = (const float*)d_in[0];
  const float* femb   = (const float*)d_in[1];
  const float* hemb   = (const float*)d_in[2];
  const float* Ww     = (const float*)d_in[3];
  const float* bw     = (const float*)d_in[4];
  const float* Wu     = (const float*)d_in[5];
  const unsigned char* mask = (const unsigned char*)d_in[6];
  float* out = (float*)d_out;
  float* ws = (float*)d_ws;

  // ---- new-path ws layout (floats)
  // hembp[Np*E]=65536 | ctx 32000 | part 68000 | flags 16 |
  // A fp16 (Mp*Kp/2 = 327680 f) | B fp16 (Np*Kp/2 = 655360 f) |
  // sc fp16 (Mp*Np/2 = 4194304 f)
  const size_t OFF_HP = 0;
  const size_t OFF_CTX = 65536;
  const size_t OFF_PART = OFF_CTX + 32000;
  const size_t OFF_FLG = OFF_PART + 68000;
  const size_t OFF_A = OFF_FLG + 16;
  const size_t OFF_B = OFF_A + (size_t)Mp * Kp / 2;
  const size_t OFF_SC = OFF_B + (size_t)Np * Kp / 2;
  const size_t NEED = (OFF_SC + (size_t)Mp * Np / 2) * 4;

  if (ws_size >= NEED) {
    float* hembp = ws + OFF_HP;
    float* ctx = ws + OFF_CTX;
    float* part = ws + OFF_PART;
    int* mflag = (int*)(ws + OFF_FLG);
    _Float16* A = (_Float16*)(ws + OFF_A);
    _Float16* B = (_Float16*)(ws + OFF_B);
    _Float16* sc = (_Float16*)(ws + OFF_SC);

    constexpr int PTOT = Fdim * Hdim + Wdim * Hdim +
                         (Mp - Fdim) * Kp / 2 + (Np - Wdim) * Kp / 2 +
                         Np * Edim / 4 + 64;  // 423488
    prep2_kernel<<<dim3((PTOT + 255) / 256), dim3(256), 0, stream>>>(
        femb, hemb, Ww, bw, Wu, mask, A, B, hembp, mflag);

    score_gemm_kernel<<<dim3(Np / 128, Mp / 128), dim3(256), 0, stream>>>(
        A, B, mask, mflag, sc);

    ctx2_kernel<<<dim3(Fdim / FTILE, 2), dim3(256), 0, stream>>>(
        sc, hembp, part);

    finalize2_kernel<<<dim3((Fdim * Edim + 255) / 256), dim3(256), 0,
                       stream>>>(part, ctx);

    out_gemv_kernel<<<dim3(Bdim), dim3(256), 0, stream>>>(values, ctx, out);
  } else {
    // ---- fallback (R5): efp | ehp2 | ctx | wusum | mflag | part
    float* efp = ws;
    float* ehp2 = efp + Fdim * Hdim;
    float* ctx = ehp2 + (size_t)Hdim * Wdim;
    float* wusum = ctx + Fdim * Edim;
    int* mflag = (int*)(wusum + 1);
    float* part = (float*)(mflag + 1);

    detect_mask_kernel<<<dim3(1), dim3(256), 0, stream>>>(mask, mflag);
    constexpr int NTOT = Fdim * Hdim + (Hdim / 2) * Wdim + 64;
    prep_fb_kernel<<<dim3((NTOT + 255) / 256), dim3(256), 0, stream>>>(
        femb, hemb, Ww, bw, Wu, efp, ehp2, wusum);
    attn_fb_kernel<<<dim3(Fdim / FTILE, FB_WCHUNKS), dim3(256), 0, stream>>>(
        efp, ehp2, Wu, wusum, mask, mflag, hemb, part);
    finalize_fb_kernel<<<dim3((Fdim * Edim + 255) / 256), dim3(256), 0,
                         stream>>>(part, ctx);
    out_gemv_kernel<<<dim3(Bdim), dim3(256), 0, stream>>>(values, ctx, out);
  }
}

// Round 9
// 86.626 us; speedup vs baseline: 1.4686x; 1.1248x over previous
//
#include <hip/hip_runtime.h>

constexpr int Fdim = 2000;
constexpr int Wdim = 4000;
constexpr int Edim = 16;
constexpr int Hdim = 64;
constexpr int Bdim = 256;
constexpr int FTILE = 4;
constexpr float kLog2e = 1.4426950408889634f;

// ---- MFMA-path padded dims
constexpr int Mp = 2048;    // padded F (grid coverage)
constexpr int Np = 4096;    // padded W
constexpr int Kp = 320;     // 5 powers x 64 h
constexpr int NWRD = Np / 32;  // 128 mask words per row

typedef float v2f __attribute__((ext_vector_type(2)));
typedef _Float16 f16x8 __attribute__((ext_vector_type(8)));
typedef float f32x4 __attribute__((ext_vector_type(4)));

__device__ __forceinline__ float fast_exp2(float x) {
#if __has_builtin(__builtin_amdgcn_exp2f)
  return __builtin_amdgcn_exp2f(x);
#else
  return exp2f(x);
#endif
}
__device__ __forceinline__ float fast_rcp(float x) {
#if __has_builtin(__builtin_amdgcn_rcpf)
  return __builtin_amdgcn_rcpf(x);
#else
  return 1.0f / x;
#endif
}
__device__ __forceinline__ v2f v2s(float x) { v2f r; r.x = x; r.y = x; return r; }
__device__ __forceinline__ v2f v2fma(v2f a, v2f b, v2f c) {
  return __builtin_elementwise_fma(a, b, c);
}
__device__ __forceinline__ float4 f4_fma_s(float s, float4 a, float4 b) {
  return make_float4(fmaf(s, a.x, b.x), fmaf(s, a.y, b.y),
                     fmaf(s, a.z, b.z), fmaf(s, a.w, b.w));
}
__device__ __forceinline__ float dev_tanh(float x) {
  return 1.0f - 2.0f * fast_rcp(fast_exp2(2.0f * kLog2e * x) + 1.0f);
}

// ---- DPP wave-64 sum (VALU pipe). Result valid in lane 63.
template <int CTRL>
__device__ __forceinline__ float dpp_part(float x) {
  return __int_as_float(
      __builtin_amdgcn_update_dpp(0, __float_as_int(x), CTRL, 0xF, 0xF, true));
}
__device__ __forceinline__ float wave64_sum(float x) {
  const float x0 = x;
  x += dpp_part<0x111>(x0);
  x += dpp_part<0x112>(x0);
  x += dpp_part<0x113>(x0);
  x += dpp_part<0x114>(x);
  x += dpp_part<0x118>(x);
  x += dpp_part<0x142>(x);
  x += dpp_part<0x143>(x);
  return x;  // lane 63 holds the full sum
}

// --- detect whether mask is 1-byte bool or 4-byte int32 -------------------
__global__ void detect_mask_kernel(const unsigned char* __restrict__ mask,
                                   int* __restrict__ flag) {
  __shared__ int any;
  if (threadIdx.x == 0) any = 0;
  __syncthreads();
  int acc = 0;
  for (int i = threadIdx.x; i < 8192; i += 256)
    if ((i & 3) != 0) acc |= mask[i];
  if (acc) atomicOr(&any, 1);
  __syncthreads();
  if (threadIdx.x == 0) *flag = (any != 0) ? 1 : 0;  // 1 = byte layout
}

// ============================================================================
// ===========================  MFMA PATH  ====================================
// ============================================================================

// prep2: A/B fp16 GEMM operands + bit-packed mask.
//   A[f][j*64+h] = tanh(s)^j (j=0..4), s = femb@Ww[:E]
//   B[w][j*64+h] = Wu[h]*{q, 1-q^2, q^3-q, q^2-q^4, -q^3}, q = tanh(hid+b)
//   mbits[f][word] bit j <=> mask[f][word*32+j] != 0 ; words>=125 zero.
__global__ __launch_bounds__(256) void prep2_kernel(
    const float* __restrict__ femb, const float* __restrict__ hemb,
    const float* __restrict__ Ww, const float* __restrict__ bw,
    const float* __restrict__ Wu, const unsigned char* __restrict__ mask,
    const int* __restrict__ mflag, _Float16* __restrict__ A,
    _Float16* __restrict__ B, unsigned int* __restrict__ mbits) {
  constexpr int PA = Fdim * Hdim;          // 128000
  constexpr int PB = PA + Wdim * Hdim;     // 384000
  constexpr int PK = PB + Fdim * NWRD;     // 640000
  int idx = blockIdx.x * 256 + threadIdx.x;
  if (idx < PA) {
    int f = idx >> 6, h = idx & 63;
    float s = 0.f;
#pragma unroll
    for (int e = 0; e < Edim; ++e)
      s = fmaf(femb[f * Edim + e], Ww[e * Hdim + h], s);
    float p = dev_tanh(s);
    _Float16* a = A + (size_t)f * Kp + h;
    float pj = 1.0f;
#pragma unroll
    for (int j = 0; j < 5; ++j) {
      a[j * 64] = (_Float16)pj;
      pj *= p;
    }
  } else if (idx < PB) {
    int jj = idx - PA;
    int w = jj >> 6, h = jj & 63;
    float t = bw[h];
#pragma unroll
    for (int e = 0; e < Edim; ++e)
      t = fmaf(hemb[w * Edim + e], Ww[(Edim + e) * Hdim + h], t);
    float q = dev_tanh(t);
    float wu = Wu[h];
    float q2 = q * q, q3 = q2 * q;
    _Float16* b = B + (size_t)w * Kp + h;
    b[0 * 64] = (_Float16)(wu * q);
    b[1 * 64] = (_Float16)(wu * (1.0f - q2));
    b[2 * 64] = (_Float16)(wu * (q3 - q));
    b[3 * 64] = (_Float16)(wu * (q2 - q2 * q2));
    b[4 * 64] = (_Float16)(-wu * q3);
  } else if (idx < PK) {
    int t = idx - PB;
    int f = t >> 7, word = t & 127;
    unsigned int bits = 0u;
    if (word < Wdim / 32) {  // 125 full words; Wdim%32==0
      const int w0 = word * 32;
      if (*mflag) {  // byte layout: 32 bytes -> 2 uint4
        const uint4* p = (const uint4*)(mask + (size_t)f * Wdim + w0);
        uint4 u0 = p[0], u1 = p[1];
        unsigned int uu[8] = {u0.x, u0.y, u0.z, u0.w, u1.x, u1.y, u1.z, u1.w};
#pragma unroll
        for (int k = 0; k < 8; ++k)
#pragma unroll
          for (int b2 = 0; b2 < 4; ++b2)
            bits |= (((uu[k] >> (8 * b2)) & 0xFFu) ? 1u : 0u) << (k * 4 + b2);
      } else {       // int32 layout: 32 ints -> 8 uint4
        const uint4* p =
            (const uint4*)((const unsigned int*)mask + (size_t)f * Wdim + w0);
#pragma unroll
        for (int k = 0; k < 8; ++k) {
          uint4 u = p[k];
          bits |= (u.x ? 1u : 0u) << (4 * k + 0);
          bits |= (u.y ? 1u : 0u) << (4 * k + 1);
          bits |= (u.z ? 1u : 0u) << (4 * k + 2);
          bits |= (u.w ? 1u : 0u) << (4 * k + 3);
        }
      }
    }
    mbits[(size_t)f * NWRD + word] = bits;
  }
}

// score_gemm: sc[f][w] = maskbit ? exp(A@B^T) : 0 (fp16), f<2000 only.
// Wave computes 32x64 via 2x4 frags of mfma 16x16x32 f16.
// grid (Np/128, Mp/64), 4 waves as 2x2 -> block tile 64x128.
__global__ __launch_bounds__(256) void score_gemm_kernel(
    const _Float16* __restrict__ A, const _Float16* __restrict__ B,
    const unsigned int* __restrict__ mbits, _Float16* __restrict__ sc) {
  const int tid = threadIdx.x;
  const int wid = tid >> 6, lane = tid & 63;
  const int wr = wid >> 1, wc = wid & 1;
  const int mwave = blockIdx.y * 64 + wr * 32;
  const int nwave = blockIdx.x * 128 + wc * 64;
  const int lrow = lane & 15, lk8 = (lane >> 4) * 8;

  f32x4 acc[2][4];
#pragma unroll
  for (int i = 0; i < 2; ++i)
#pragma unroll
    for (int j = 0; j < 4; ++j) acc[i][j] = (f32x4){0.f, 0.f, 0.f, 0.f};

  const _Float16* Ab = A + (size_t)(mwave + lrow) * Kp + lk8;
  const _Float16* Bb = B + (size_t)(nwave + lrow) * Kp + lk8;
#pragma unroll 2
  for (int ks = 0; ks < Kp / 32; ++ks) {
    f16x8 a[2], b[4];
#pragma unroll
    for (int i = 0; i < 2; ++i)
      a[i] = *(const f16x8*)(Ab + (size_t)i * 16 * Kp + ks * 32);
#pragma unroll
    for (int j = 0; j < 4; ++j)
      b[j] = *(const f16x8*)(Bb + (size_t)j * 16 * Kp + ks * 32);
#pragma unroll
    for (int mi = 0; mi < 2; ++mi)
#pragma unroll
      for (int nj = 0; nj < 4; ++nj)
        acc[mi][nj] = __builtin_amdgcn_mfma_f32_16x16x32_f16(
            a[mi], b[nj], acc[mi][nj], 0, 0, 0);
  }

  const int rbase = (lane >> 4) * 4;
  const int wq = nwave >> 5;  // even -> uint2 aligned
#pragma unroll
  for (int mi = 0; mi < 2; ++mi) {
#pragma unroll
    for (int r = 0; r < 4; ++r) {
      const int f = mwave + mi * 16 + rbase + r;
      if (f < Fdim) {
        uint2 mb = *(const uint2*)(mbits + (size_t)f * NWRD + wq);
#pragma unroll
        for (int nj = 0; nj < 4; ++nj) {
          unsigned int half = (nj < 2) ? mb.x : mb.y;
          float m = (float)((half >> ((nj & 1) * 16 + lrow)) & 1u);
          float v = fast_exp2(acc[mi][nj][r] * kLog2e) * m;
          sc[(size_t)f * Np + nwave + nj * 16 + lrow] = (_Float16)v;
        }
      }
    }
  }
}

// ctx2: den[f] = sum_w sc, num[f][e] = sum_w sc*hemb[w][e]; DPP reduce.
__global__ __launch_bounds__(256) void ctx2_kernel(
    const _Float16* __restrict__ sc, const float* __restrict__ hemb,
    float* __restrict__ part) {
  const int f0 = blockIdx.x * FTILE;
  const int chunk = blockIdx.y;  // 0,1
  const int tid = threadIdx.x;
  const int w0 = chunk * 2048 + tid * 8;
  const bool wok = (w0 < Wdim);  // Wdim%8==0 -> all-or-nothing

  __shared__ float s_red[4][FTILE][20];

  float den[FTILE] = {0.f, 0.f, 0.f, 0.f};
  v2f cacc[FTILE][8];
#pragma unroll
  for (int fi = 0; fi < FTILE; ++fi)
#pragma unroll
    for (int t = 0; t < 8; ++t) cacc[fi][t] = v2s(0.f);

  if (wok) {
    f16x8 scv[FTILE];
#pragma unroll
    for (int fi = 0; fi < FTILE; ++fi)
      scv[fi] = *(const f16x8*)(sc + (size_t)(f0 + fi) * Np + w0);
#pragma unroll
    for (int jw = 0; jw < 8; ++jw) {
      const float4* h4 = (const float4*)(hemb + (size_t)(w0 + jw) * Edim);
      float4 h0 = h4[0], h1 = h4[1], h2 = h4[2], h3 = h4[3];
      v2f hv[8];
      hv[0].x = h0.x; hv[0].y = h0.y; hv[1].x = h0.z; hv[1].y = h0.w;
      hv[2].x = h1.x; hv[2].y = h1.y; hv[3].x = h1.z; hv[3].y = h1.w;
      hv[4].x = h2.x; hv[4].y = h2.y; hv[5].x = h2.z; hv[5].y = h2.w;
      hv[6].x = h3.x; hv[6].y = h3.y; hv[7].x = h3.z; hv[7].y = h3.w;
#pragma unroll
      for (int fi = 0; fi < FTILE; ++fi) {
        float s = (float)scv[fi][jw];
        den[fi] += s;
#pragma unroll
        for (int t = 0; t < 8; ++t)
          cacc[fi][t] = v2fma(v2s(s), hv[t], cacc[fi][t]);
      }
    }
  }

  const int lane = tid & 63, wv = tid >> 6;
#pragma unroll
  for (int fi = 0; fi < FTILE; ++fi) {
    float d = wave64_sum(den[fi]);
    if (lane == 63) s_red[wv][fi][16] = d;
#pragma unroll
    for (int t = 0; t < 8; ++t) {
      float a = wave64_sum(cacc[fi][t].x);
      float b = wave64_sum(cacc[fi][t].y);
      if (lane == 63) {
        s_red[wv][fi][2 * t] = a;
        s_red[wv][fi][2 * t + 1] = b;
      }
    }
  }
  __syncthreads();
  if (tid < FTILE * 17) {
    int fi = tid / 17, k = tid % 17;
    float tot = s_red[0][fi][k] + s_red[1][fi][k] + s_red[2][fi][k] +
                s_red[3][fi][k];
    part[((size_t)(f0 + fi) * 2 + chunk) * 17 + k] = tot;
  }
}

__global__ __launch_bounds__(256) void finalize2_kernel(
    const float* __restrict__ part, float* __restrict__ ctx) {
  int idx = blockIdx.x * 256 + threadIdx.x;
  if (idx >= Fdim * Edim) return;
  int f = idx >> 4, e = idx & 15;
  const float* p = part + (size_t)f * 2 * 17;
  float den = p[16] + p[17 + 16];
  float num = p[e] + p[17 + e];
  ctx[idx] = num / den;
}

// ============================================================================
// =====================  FALLBACK PATH (R5, proven)  =========================
// ============================================================================
constexpr int FB_WCHUNKS = 4;
constexpr int FB_WTILE = 1024;
constexpr int FB_NW = 4;

__global__ __launch_bounds__(256) void prep_fb_kernel(
    const float* __restrict__ femb, const float* __restrict__ hemb,
    const float* __restrict__ Ww, const float* __restrict__ bw,
    const float* __restrict__ Wu,
    float* __restrict__ efp, float* __restrict__ ehp2,
    float* __restrict__ wusum) {
  constexpr float S = 2.0f * kLog2e;
  constexpr int NF = Fdim * Hdim;
  constexpr int NH2 = (Hdim / 2) * Wdim;
  int idx = blockIdx.x * 256 + threadIdx.x;
  if (idx < NF) {
    int f = idx >> 6, h = idx & 63;
    float acc = bw[h];
#pragma unroll
    for (int e = 0; e < Edim; ++e)
      acc = fmaf(femb[f * Edim + e], Ww[e * Hdim + h], acc);
    efp[idx] = fast_exp2(acc * S);
  } else if (idx < NF + NH2) {
    int j = idx - NF;
    int h2 = j / Wdim, w = j - h2 * Wdim;
    float a0 = 0.f, a1 = 0.f;
#pragma unroll
    for (int e = 0; e < Edim; ++e) {
      float he = hemb[w * Edim + e];
      a0 = fmaf(he, Ww[(Edim + e) * Hdim + 2 * h2 + 0], a0);
      a1 = fmaf(he, Ww[(Edim + e) * Hdim + 2 * h2 + 1], a1);
    }
    ((float2*)ehp2)[h2 * Wdim + w] =
        make_float2(fast_exp2(a0 * S), fast_exp2(a1 * S));
  } else if (idx < NF + NH2 + 64) {
    int l = idx - (NF + NH2);
    float s = Wu[l];
#pragma unroll
    for (int o = 32; o > 0; o >>= 1) s += __shfl_down(s, o, 64);
    if (l == 0) *wusum = s;
  }
}

__global__ __launch_bounds__(256) void attn_fb_kernel(
    const float* __restrict__ efp, const float* __restrict__ ehp2,
    const float* __restrict__ Wu, const float* __restrict__ wusum_p,
    const unsigned char* mask_b, const int* __restrict__ mflag,
    const float* __restrict__ hemb, float* __restrict__ part) {
  const int f0 = blockIdx.x * FTILE;
  const int chunk = blockIdx.y;
  const int tid = threadIdx.x;

  __shared__ float4 s_fpA[Hdim / 2];
  __shared__ float4 s_fpB[Hdim / 2];
  __shared__ float2 s_wu2[Hdim / 2];
  __shared__ float s_red[4][FTILE][20];

  if (tid < Hdim / 2) {
    const int h2 = tid;
    float2 p0 = *(const float2*)(efp + (f0 + 0) * Hdim + 2 * h2);
    float2 p1 = *(const float2*)(efp + (f0 + 1) * Hdim + 2 * h2);
    float2 p2 = *(const float2*)(efp + (f0 + 2) * Hdim + 2 * h2);
    float2 p3 = *(const float2*)(efp + (f0 + 3) * Hdim + 2 * h2);
    s_fpA[h2] = make_float4(p0.x, p1.x, p2.x, p3.x);
    s_fpB[h2] = make_float4(p0.y, p1.y, p2.y, p3.y);
    float2 wu = *(const float2*)(Wu + 2 * h2);
    s_wu2[h2] = make_float2(2.0f * wu.x, 2.0f * wu.y);
  }
  __syncthreads();

  const int mbyte = *mflag;
  const float wls = (*wusum_p) * kLog2e;

  const int w0 = chunk * FB_WTILE + tid * FB_NW;
  const bool wok = (w0 < Wdim);
  const int wcl = wok ? w0 : (Wdim - FB_NW);

  float sneg[FTILE][FB_NW];
#pragma unroll
  for (int fi = 0; fi < FTILE; ++fi)
#pragma unroll
    for (int j = 0; j < FB_NW; ++j) sneg[fi][j] = 0.f;

#pragma unroll 4
  for (int h2 = 0; h2 < Hdim / 2; ++h2) {
    const float* row = ehp2 + ((size_t)h2 * Wdim + wcl) * 2;
    float4 ea = *(const float4*)(row);
    float4 eb = *(const float4*)(row + 4);
    float4 fpA = s_fpA[h2];
    float4 fpB = s_fpB[h2];
    float2 wu = s_wu2[h2];
    float e0[FB_NW] = {ea.x, ea.z, eb.x, eb.z};
    float e1[FB_NW] = {ea.y, ea.w, eb.y, eb.w};
    float fA[4] = {fpA.x, fpA.y, fpA.z, fpA.w};
    float fB[4] = {fpB.x, fpB.y, fpB.z, fpB.w};
#pragma unroll
    for (int j = 0; j < FB_NW; ++j)
#pragma unroll
      for (int fi = 0; fi < FTILE; ++fi) {
        float d0 = fmaf(fA[fi], e0[j], 1.0f);
        float d1 = fmaf(fB[fi], e1[j], 1.0f);
        float num = fmaf(wu.y, d0, wu.x * d1);
        sneg[fi][j] = fmaf(num, fast_rcp(d0 * d1), sneg[fi][j]);
      }
  }

  float mbit[FTILE][FB_NW];
  if (mbyte) {
#pragma unroll
    for (int fi = 0; fi < FTILE; ++fi) {
      unsigned int m =
          *(const unsigned int*)(mask_b + (size_t)(f0 + fi) * Wdim + wcl);
#pragma unroll
      for (int j = 0; j < FB_NW; ++j)
        mbit[fi][j] = wok ? (float)((m >> (8 * j)) & 1u) : 0.f;
    }
  } else {
    const int* mask_i = (const int*)mask_b;
#pragma unroll
    for (int fi = 0; fi < FTILE; ++fi) {
      uint4 m4 = *(const uint4*)(mask_i + (size_t)(f0 + fi) * Wdim + wcl);
      unsigned int mm[FB_NW] = {m4.x, m4.y, m4.z, m4.w};
#pragma unroll
      for (int j = 0; j < FB_NW; ++j)
        mbit[fi][j] = (wok && mm[j]) ? 1.f : 0.f;
    }
  }

  float den[FTILE] = {0.f, 0.f, 0.f, 0.f};
  float4 cacc[FTILE][4];
#pragma unroll
  for (int fi = 0; fi < FTILE; ++fi)
#pragma unroll
    for (int q = 0; q < 4; ++q) cacc[fi][q] = make_float4(0.f, 0.f, 0.f, 0.f);

  const float4* h4 = (const float4*)(hemb + (size_t)wcl * Edim);
#pragma unroll
  for (int j = 0; j < FB_NW; ++j) {
    float4 hr0 = h4[j * 4 + 0], hr1 = h4[j * 4 + 1];
    float4 hr2 = h4[j * 4 + 2], hr3 = h4[j * 4 + 3];
#pragma unroll
    for (int fi = 0; fi < FTILE; ++fi) {
      float sc = fast_exp2(fmaf(sneg[fi][j], -kLog2e, wls)) * mbit[fi][j];
      den[fi] += sc;
      cacc[fi][0] = f4_fma_s(sc, hr0, cacc[fi][0]);
      cacc[fi][1] = f4_fma_s(sc, hr1, cacc[fi][1]);
      cacc[fi][2] = f4_fma_s(sc, hr2, cacc[fi][2]);
      cacc[fi][3] = f4_fma_s(sc, hr3, cacc[fi][3]);
    }
  }

  const int lane = tid & 63, wv = tid >> 6;
#pragma unroll
  for (int fi = 0; fi < FTILE; ++fi) {
    float d = wave64_sum(den[fi]);
    if (lane == 63) s_red[wv][fi][16] = d;
#pragma unroll
    for (int q = 0; q < 4; ++q) {
      float cx = wave64_sum(cacc[fi][q].x);
      float cy = wave64_sum(cacc[fi][q].y);
      float cz = wave64_sum(cacc[fi][q].z);
      float cw = wave64_sum(cacc[fi][q].w);
      if (lane == 63) {
        s_red[wv][fi][4 * q + 0] = cx;
        s_red[wv][fi][4 * q + 1] = cy;
        s_red[wv][fi][4 * q + 2] = cz;
        s_red[wv][fi][4 * q + 3] = cw;
      }
    }
  }
  __syncthreads();
  if (tid < FTILE * 17) {
    int fi = tid / 17, k = tid % 17;
    float tot = s_red[0][fi][k] + s_red[1][fi][k] + s_red[2][fi][k] +
                s_red[3][fi][k];
    part[((f0 + fi) * FB_WCHUNKS + chunk) * 17 + k] = tot;
  }
}

__global__ __launch_bounds__(256) void finalize_fb_kernel(
    const float* __restrict__ part, float* __restrict__ ctx) {
  int idx = blockIdx.x * 256 + threadIdx.x;
  if (idx >= Fdim * Edim) return;
  int f = idx >> 4, e = idx & 15;
  const float* p = part + f * FB_WCHUNKS * 17;
  float den = 0.f, num = 0.f;
#pragma unroll
  for (int c = 0; c < FB_WCHUNKS; ++c) {
    den += p[c * 17 + 16];
    num += p[c * 17 + e];
  }
  ctx[idx] = num / den;
}

// --- shared: out[b][e] = sum_f values[b][f] * ctx[f][e] ---------------------
__global__ __launch_bounds__(256) void out_gemv_kernel(
    const float* __restrict__ values, const float* __restrict__ ctx,
    float* __restrict__ out) {
  const int b = blockIdx.x, tid = threadIdx.x;
  float acc[Edim];
#pragma unroll
  for (int e = 0; e < Edim; ++e) acc[e] = 0.f;
  for (int f = tid; f < Fdim; f += 256) {
    float v = values[b * Fdim + f];
    const float4* c4 = (const float4*)(ctx + f * Edim);
    float4 c0 = c4[0], c1 = c4[1], c2 = c4[2], c3 = c4[3];
    float cr[Edim] = {c0.x, c0.y, c0.z, c0.w, c1.x, c1.y, c1.z, c1.w,
                      c2.x, c2.y, c2.z, c2.w, c3.x, c3.y, c3.z, c3.w};
#pragma unroll
    for (int e = 0; e < Edim; ++e) acc[e] = fmaf(v, cr[e], acc[e]);
  }
  __shared__ float s_red[4][Edim];
  const int lane = tid & 63, wv = tid >> 6;
#pragma unroll
  for (int e = 0; e < Edim; ++e) {
    float a = wave64_sum(acc[e]);
    if (lane == 63) s_red[wv][e] = a;
  }
  __syncthreads();
  if (tid < Edim)
    out[b * Edim + tid] =
        s_red[0][tid] + s_red[1][tid] + s_red[2][tid] + s_red[3][tid];
}

extern "C" void kernel_launch(void* const* d_in, const int* in_sizes, int n_in,
                              void* d_out, int out_size, void* d_ws,
                              size_t ws_size, hipStream_t stream) {
  const float* values = (const float*)d_in[0];
  const float* femb   = (const float*)d_in[1];
  const float* hemb   = (const float*)d_in[2];
  const float* Ww     = (const float*)d_in[3];
  const float* bw     = (const float*)d_in[4];
  const float* Wu     = (const float*)d_in[5];
  const unsigned char* mask = (const unsigned char*)d_in[6];
  float* out = (float*)d_out;
  float* ws = (float*)d_ws;

  // ---- MFMA-path ws layout (float units):
  // mflag 16 | mbits[F*128]=256000 | A fp16 (Mp*Kp/2=327680; part/ctx reuse
  // this region after gemm) | B fp16 (Np*Kp/2=655360) | sc fp16 [F][Np]
  const size_t OFF_FLG = 0;
  const size_t OFF_MB = 16;
  const size_t OFF_A = OFF_MB + (size_t)Fdim * NWRD;       // 256016
  const size_t OFF_B = OFF_A + (size_t)Mp * Kp / 2;        // 583696
  const size_t OFF_SC = OFF_B + (size_t)Np * Kp / 2;       // 1239056
  const size_t NEED = (OFF_SC + (size_t)Fdim * Np / 2) * 4;  // ~21.34 MB

  if (ws_size >= NEED) {
    int* mflag = (int*)(ws + OFF_FLG);
    unsigned int* mbits = (unsigned int*)(ws + OFF_MB);
    _Float16* A = (_Float16*)(ws + OFF_A);
    _Float16* B = (_Float16*)(ws + OFF_B);
    _Float16* sc = (_Float16*)(ws + OFF_SC);
    float* part = ws + OFF_A;          // reuse A region (dead after gemm)
    float* ctx = ws + OFF_A + 68000;   // 68000 + 32000 << 327680

    detect_mask_kernel<<<dim3(1), dim3(256), 0, stream>>>(mask, mflag);

    constexpr int PTOT = Fdim * Hdim + Wdim * Hdim + Fdim * NWRD;  // 640000
    prep2_kernel<<<dim3((PTOT + 255) / 256), dim3(256), 0, stream>>>(
        femb, hemb, Ww, bw, Wu, mask, mflag, A, B, mbits);

    score_gemm_kernel<<<dim3(Np / 128, Mp / 64), dim3(256), 0, stream>>>(
        A, B, mbits, sc);

    ctx2_kernel<<<dim3(Fdim / FTILE, 2), dim3(256), 0, stream>>>(
        sc, hemb, part);

    finalize2_kernel<<<dim3((Fdim * Edim + 255) / 256), dim3(256), 0,
                       stream>>>(part, ctx);

    out_gemv_kernel<<<dim3(Bdim), dim3(256), 0, stream>>>(values, ctx, out);
  } else {
    // ---- fallback (R5): efp | ehp2 | ctx | wusum | mflag | part
    float* efp = ws;
    float* ehp2 = efp + Fdim * Hdim;
    float* ctx = ehp2 + (size_t)Hdim * Wdim;
    float* wusum = ctx + Fdim * Edim;
    int* mflag = (int*)(wusum + 1);
    float* part = (float*)(mflag + 1);

    detect_mask_kernel<<<dim3(1), dim3(256), 0, stream>>>(mask, mflag);
    constexpr int NTOT = Fdim * Hdim + (Hdim / 2) * Wdim + 64;
    prep_fb_kernel<<<dim3((NTOT + 255) / 256), dim3(256), 0, stream>>>(
        femb, hemb, Ww, bw, Wu, efp, ehp2, wusum);
    attn_fb_kernel<<<dim3(Fdim / FTILE, FB_WCHUNKS), dim3(256), 0, stream>>>(
        efp, ehp2, Wu, wusum, mask, mflag, hemb, part);
    finalize_fb_kernel<<<dim3((Fdim * Edim + 255) / 256), dim3(256), 0,
                         stream>>>(part, ctx);
    out_gemv_kernel<<<dim3(Bdim), dim3(256), 0, stream>>>(values, ctx, out);
  }
}

// Round 11
// 68.521 us; speedup vs baseline: 1.8566x; 1.2642x over previous
//
#include <hip/hip_runtime.h>

constexpr int Fdim = 2000;
constexpr int Wdim = 4000;
constexpr int Edim = 16;
constexpr int Hdim = 64;
constexpr int Bdim = 256;
constexpr float kLog2e = 1.4426950408889634f;

// ---- MFMA-path padded dims
constexpr int Mp = 2048;        // padded F
constexpr int Np = 4096;        // padded W
constexpr int Kp = 320;         // 5 tanh powers x 64 h
constexpr int NWRD = Np / 32;   // 128 mask words per (padded) row
constexpr int NCHUNK = Np / 64; // 64 w-chunks of partials

typedef _Float16 f16x8 __attribute__((ext_vector_type(8)));
typedef _Float16 f16x2 __attribute__((ext_vector_type(2)));
typedef float f32x4 __attribute__((ext_vector_type(4)));

__device__ __forceinline__ float fast_exp2(float x) {
#if __has_builtin(__builtin_amdgcn_exp2f)
  return __builtin_amdgcn_exp2f(x);
#else
  return exp2f(x);
#endif
}
__device__ __forceinline__ float fast_rcp(float x) {
#if __has_builtin(__builtin_amdgcn_rcpf)
  return __builtin_amdgcn_rcpf(x);
#else
  return 1.0f / x;
#endif
}
__device__ __forceinline__ float dev_tanh(float x) {
  return 1.0f - 2.0f * fast_rcp(fast_exp2(2.0f * kLog2e * x) + 1.0f);
}
__device__ __forceinline__ f16x2 pack_f16(float a, float b) {
  return __builtin_bit_cast(f16x2, __builtin_amdgcn_cvt_pkrtz(a, b));
}

// ---- DPP wave-64 sum (VALU pipe). Result valid in lane 63.
template <int CTRL>
__device__ __forceinline__ float dpp_part(float x) {
  return __int_as_float(
      __builtin_amdgcn_update_dpp(0, __float_as_int(x), CTRL, 0xF, 0xF, true));
}
__device__ __forceinline__ float wave64_sum(float x) {
  const float x0 = x;
  x += dpp_part<0x111>(x0);
  x += dpp_part<0x112>(x0);
  x += dpp_part<0x113>(x0);
  x += dpp_part<0x114>(x);
  x += dpp_part<0x118>(x);
  x += dpp_part<0x142>(x);
  x += dpp_part<0x143>(x);
  return x;
}

// --- detect whether mask is 1-byte bool or 4-byte int32 -------------------
__global__ void detect_mask_kernel(const unsigned char* __restrict__ mask,
                                   int* __restrict__ flag) {
  __shared__ int any;
  if (threadIdx.x == 0) any = 0;
  __syncthreads();
  int acc = 0;
  for (int i = threadIdx.x; i < 8192; i += 256)
    if ((i & 3) != 0) acc |= mask[i];
  if (acc) atomicOr(&any, 1);
  __syncthreads();
  if (threadIdx.x == 0) *flag = (any != 0) ? 1 : 0;  // 1 = byte layout
}

// prep2: fp16 GEMM operands + bit-packed mask + hemb B-fragments.
//   A[f][j*64+h] = tanh(s)^j (j=0..4), s = femb@Ww[:E]; rows >=Fdim zeroed
//   B[w][j*64+h] = Wu[h]*{q,1-q^2,q^3-q,q^2-q^4,-q^3}, q=tanh(hid+b); pad 0
//   mbits[f][word] (2048 rows; pad rows/words zero)
//   hembB[widx][lane][i] = hemb[widx*32+(lane>>4)*8+i][lane&15]  (fp16 frags)
__global__ __launch_bounds__(256) void prep2_kernel(
    const float* __restrict__ femb, const float* __restrict__ hemb,
    const float* __restrict__ Ww, const float* __restrict__ bw,
    const float* __restrict__ Wu, const unsigned char* __restrict__ mask,
    const int* __restrict__ mflag, _Float16* __restrict__ A,
    _Float16* __restrict__ B, unsigned int* __restrict__ mbits,
    _Float16* __restrict__ hembB) {
  constexpr int PA = Fdim * Hdim;                  // 128000 A main
  constexpr int PAZ = PA + (Mp - Fdim) * Kp / 2;   // +7680 A pad (u32)
  constexpr int PB = PAZ + Wdim * Hdim;            // +256000 B main
  constexpr int PBZ = PB + (Np - Wdim) * Kp / 2;   // +15360 B pad (u32)
  constexpr int PM = PBZ + Mp * NWRD;              // +262144 mbits
  constexpr int PH = PM + (Np / 32) * 64;          // +8192 hembB
  int idx = blockIdx.x * 256 + threadIdx.x;
  if (idx < PA) {
    int f = idx >> 6, h = idx & 63;
    float s = 0.f;
#pragma unroll
    for (int e = 0; e < Edim; ++e)
      s = fmaf(femb[f * Edim + e], Ww[e * Hdim + h], s);
    float p = dev_tanh(s);
    _Float16* a = A + (size_t)f * Kp + h;
    float pj = 1.0f;
#pragma unroll
    for (int j = 0; j < 5; ++j) {
      a[j * 64] = (_Float16)pj;
      pj *= p;
    }
  } else if (idx < PAZ) {
    ((unsigned int*)(A + (size_t)Fdim * Kp))[idx - PA] = 0u;
  } else if (idx < PB) {
    int jj = idx - PAZ;
    int w = jj >> 6, h = jj & 63;
    float t = bw[h];
#pragma unroll
    for (int e = 0; e < Edim; ++e)
      t = fmaf(hemb[w * Edim + e], Ww[(Edim + e) * Hdim + h], t);
    float q = dev_tanh(t);
    float wu = Wu[h];
    float q2 = q * q, q3 = q2 * q;
    _Float16* b = B + (size_t)w * Kp + h;
    b[0 * 64] = (_Float16)(wu * q);
    b[1 * 64] = (_Float16)(wu * (1.0f - q2));
    b[2 * 64] = (_Float16)(wu * (q3 - q));
    b[3 * 64] = (_Float16)(wu * (q2 - q2 * q2));
    b[4 * 64] = (_Float16)(-wu * q3);
  } else if (idx < PBZ) {
    ((unsigned int*)(B + (size_t)Wdim * Kp))[idx - PB] = 0u;
  } else if (idx < PM) {
    int t = idx - PBZ;
    int f = t >> 7, word = t & 127;
    unsigned int bits = 0u;
    if (f < Fdim && word < Wdim / 32) {
      const int w0 = word * 32;
      if (*mflag) {  // byte layout
        const uint4* p = (const uint4*)(mask + (size_t)f * Wdim + w0);
        uint4 u0 = p[0], u1 = p[1];
        unsigned int uu[8] = {u0.x, u0.y, u0.z, u0.w, u1.x, u1.y, u1.z, u1.w};
#pragma unroll
        for (int k = 0; k < 8; ++k)
#pragma unroll
          for (int b2 = 0; b2 < 4; ++b2)
            bits |= (((uu[k] >> (8 * b2)) & 0xFFu) ? 1u : 0u) << (k * 4 + b2);
      } else {       // int32 layout
        const uint4* p =
            (const uint4*)((const unsigned int*)mask + (size_t)f * Wdim + w0);
#pragma unroll
        for (int k = 0; k < 8; ++k) {
          uint4 u = p[k];
          bits |= (u.x ? 1u : 0u) << (4 * k + 0);
          bits |= (u.y ? 1u : 0u) << (4 * k + 1);
          bits |= (u.z ? 1u : 0u) << (4 * k + 2);
          bits |= (u.w ? 1u : 0u) << (4 * k + 3);
        }
      }
    }
    mbits[(size_t)f * NWRD + word] = bits;
  } else if (idx < PH) {
    int j = idx - PM;
    int lane = j & 63;
    int e = lane & 15;
    int wb = (j >> 6) * 32 + (lane >> 4) * 8;
    f16x8 v;
#pragma unroll
    for (int i = 0; i < 8; ++i) {
      int w = wb + i;
      v[i] = (w < Wdim) ? (_Float16)hemb[(size_t)w * Edim + e] : (_Float16)0.f;
    }
    *(f16x8*)(hembB + (size_t)j * 8) = v;
  }
}

// score_ctx: fused. Wave = 32f x 64w. First GEMM SWAPPED: mfma(B_w, A_f)
// -> D col=f (lane&15), row=w ((lane>>4)*4+r). Epilogue: exp2*maskbit, fp16
// -> per-wave XOR-swizzled LDS tile [32f][64w]. Second GEMM: mfma(sc_lds,
// hembB) contracting w -> num[32f][16e]; den via in-reg sum + shfl_xor.
__global__ __launch_bounds__(256) void score_ctx_kernel(
    const _Float16* __restrict__ A, const _Float16* __restrict__ B,
    const unsigned int* __restrict__ mbits, const _Float16* __restrict__ hembB,
    float* __restrict__ part_num, float* __restrict__ part_den) {
  __shared__ __align__(16) char smem[16384];  // 4 KB per wave
  const int tid = threadIdx.x;
  const int wid = tid >> 6, lane = tid & 63;
  const int wr = wid >> 1, wc = wid & 1;
  const int fbase = blockIdx.y * 64 + wr * 32;
  const int wbase = blockIdx.x * 128 + wc * 64;
  const int lrow = lane & 15, g = lane >> 4;

  f32x4 accT[4][2];  // [mw (w-frag)][nf (f-frag)]
#pragma unroll
  for (int mw = 0; mw < 4; ++mw)
#pragma unroll
    for (int nf = 0; nf < 2; ++nf) accT[mw][nf] = (f32x4){0.f, 0.f, 0.f, 0.f};

  const _Float16* Bw = B + (size_t)(wbase + lrow) * Kp + g * 8;
  const _Float16* Af = A + (size_t)(fbase + lrow) * Kp + g * 8;
#pragma unroll 2
  for (int ks = 0; ks < Kp / 32; ++ks) {
    f16x8 bw[4], af[2];
#pragma unroll
    for (int mw = 0; mw < 4; ++mw)
      bw[mw] = *(const f16x8*)(Bw + (size_t)mw * 16 * Kp + ks * 32);
#pragma unroll
    for (int nf = 0; nf < 2; ++nf)
      af[nf] = *(const f16x8*)(Af + (size_t)nf * 16 * Kp + ks * 32);
#pragma unroll
    for (int mw = 0; mw < 4; ++mw)
#pragma unroll
      for (int nf = 0; nf < 2; ++nf)
        accT[mw][nf] = __builtin_amdgcn_mfma_f32_16x16x32_f16(
            bw[mw], af[nf], accT[mw][nf], 0, 0, 0);
  }

  // ---- epilogue: exp2 * maskbit -> fp16 -> swizzled LDS; den partials
  char* sbase = smem + wid * 4096;
  float denp[2] = {0.f, 0.f};
#pragma unroll
  for (int nf = 0; nf < 2; ++nf) {
    const int f = fbase + nf * 16 + lrow;
    const uint2 mb = *(const uint2*)(mbits + (size_t)f * NWRD + (wbase >> 5));
    const int fl = nf * 16 + lrow;
    const int sw = (fl & 7) << 4;
#pragma unroll
    for (int mw = 0; mw < 4; ++mw) {
      float v[4];
#pragma unroll
      for (int r = 0; r < 4; ++r) {
        const int wl = mw * 16 + g * 4 + r;
        const unsigned int word = (wl < 32) ? mb.x : mb.y;
        const float m = (float)((word >> (wl & 31)) & 1u);
        v[r] = fast_exp2(accT[mw][nf][r] * kLog2e) * m;
        denp[nf] += v[r];
      }
      const int wb0 = (mw * 16 + g * 4) * 2;
      *(f16x2*)(sbase + fl * 128 + ((wb0 + 0) ^ sw)) = pack_f16(v[0], v[1]);
      *(f16x2*)(sbase + fl * 128 + ((wb0 + 4) ^ sw)) = pack_f16(v[2], v[3]);
    }
  }

  // ---- second GEMM: num[32f][16e] over this wave's 64 w
  f32x4 numT[2];
#pragma unroll
  for (int nf = 0; nf < 2; ++nf) numT[nf] = (f32x4){0.f, 0.f, 0.f, 0.f};
#pragma unroll
  for (int kstep = 0; kstep < 2; ++kstep) {
    const f16x8 hb = *(const f16x8*)(
        hembB + ((size_t)(wbase >> 5) + kstep) * 512 + lane * 8);
#pragma unroll
    for (int nf = 0; nf < 2; ++nf) {
      const int fl = nf * 16 + lrow;
      const f16x8 scf = *(const f16x8*)(
          sbase + fl * 128 + ((kstep * 64 + g * 16) ^ ((fl & 7) << 4)));
      numT[nf] = __builtin_amdgcn_mfma_f32_16x16x32_f16(scf, hb, numT[nf],
                                                        0, 0, 0);
    }
  }

  // ---- den: sum across the 4 lane-groups (same f, different g)
#pragma unroll
  for (int nf = 0; nf < 2; ++nf) {
    float d = denp[nf];
    d += __shfl_xor(d, 16, 64);
    d += __shfl_xor(d, 32, 64);
    denp[nf] = d;
  }

  // ---- write partials for this (64-w chunk)
  const int chunk = blockIdx.x * 2 + wc;
  if (lane < 16) {
#pragma unroll
    for (int nf = 0; nf < 2; ++nf)
      part_den[(size_t)chunk * Mp + fbase + nf * 16 + lrow] = denp[nf];
  }
#pragma unroll
  for (int nf = 0; nf < 2; ++nf)
#pragma unroll
    for (int r = 0; r < 4; ++r) {
      const int f = fbase + nf * 16 + g * 4 + r;
      part_num[((size_t)chunk * Mp + f) * Edim + lrow] = numT[nf][r];
    }
}

// finalize: ctx[f][e] = sum_c num / sum_c den
__global__ __launch_bounds__(256) void finalize2_kernel(
    const float* __restrict__ part_num, const float* __restrict__ part_den,
    float* __restrict__ ctx) {
  int idx = blockIdx.x * 256 + threadIdx.x;
  if (idx >= Fdim * Edim) return;
  int f = idx >> 4, e = idx & 15;
  float num = 0.f, den = 0.f;
#pragma unroll 4
  for (int c = 0; c < NCHUNK; ++c) {
    num += part_num[((size_t)c * Mp + f) * Edim + e];
    den += part_den[(size_t)c * Mp + f];
  }
  ctx[idx] = num / den;
}

// out[b][e] = sum_f values[b][f] * ctx[f][e]
__global__ __launch_bounds__(256) void out_gemv_kernel(
    const float* __restrict__ values, const float* __restrict__ ctx,
    float* __restrict__ out) {
  const int b = blockIdx.x, tid = threadIdx.x;
  float acc[Edim];
#pragma unroll
  for (int e = 0; e < Edim; ++e) acc[e] = 0.f;
  for (int f = tid; f < Fdim; f += 256) {
    float v = values[b * Fdim + f];
    const float4* c4 = (const float4*)(ctx + f * Edim);
    float4 c0 = c4[0], c1 = c4[1], c2 = c4[2], c3 = c4[3];
    float cr[Edim] = {c0.x, c0.y, c0.z, c0.w, c1.x, c1.y, c1.z, c1.w,
                      c2.x, c2.y, c2.z, c2.w, c3.x, c3.y, c3.z, c3.w};
#pragma unroll
    for (int e = 0; e < Edim; ++e) acc[e] = fmaf(v, cr[e], acc[e]);
  }
  __shared__ float s_red[4][Edim];
  const int lane = tid & 63, wv = tid >> 6;
#pragma unroll
  for (int e = 0; e < Edim; ++e) {
    float a = wave64_sum(acc[e]);
    if (lane == 63) s_red[wv][e] = a;
  }
  __syncthreads();
  if (tid < Edim)
    out[b * Edim + tid] =
        s_red[0][tid] + s_red[1][tid] + s_red[2][tid] + s_red[3][tid];
}

extern "C" void kernel_launch(void* const* d_in, const int* in_sizes, int n_in,
                              void* d_out, int out_size, void* d_ws,
                              size_t ws_size, hipStream_t stream) {
  const float* values = (const float*)d_in[0];
  const float* femb   = (const float*)d_in[1];
  const float* hemb   = (const float*)d_in[2];
  const float* Ww     = (const float*)d_in[3];
  const float* bw     = (const float*)d_in[4];
  const float* Wu     = (const float*)d_in[5];
  const unsigned char* mask = (const unsigned char*)d_in[6];
  float* out = (float*)d_out;
  float* ws = (float*)d_ws;

  // ws layout (float units). Total ~14.2 MB (< 21.34 MB proven in R8).
  const size_t OFF_FLG = 0;                                  // 16
  const size_t OFF_MB = 16;                                  // Mp*NWRD = 262144
  const size_t OFF_A = OFF_MB + (size_t)Mp * NWRD;           // Mp*Kp/2 = 327680
  const size_t OFF_B = OFF_A + (size_t)Mp * Kp / 2;          // Np*Kp/2 = 655360
  const size_t OFF_HB = OFF_B + (size_t)Np * Kp / 2;         // 128*512/2 = 32768
  const size_t OFF_PN = OFF_HB + 32768;                      // 64*2048*16 = 2097152
  const size_t OFF_PD = OFF_PN + (size_t)NCHUNK * Mp * Edim; // 64*2048 = 131072
  const size_t OFF_CTX = OFF_PD + (size_t)NCHUNK * Mp;       // 32000

  int* mflag = (int*)(ws + OFF_FLG);
  unsigned int* mbits = (unsigned int*)(ws + OFF_MB);
  _Float16* A = (_Float16*)(ws + OFF_A);
  _Float16* B = (_Float16*)(ws + OFF_B);
  _Float16* hembB = (_Float16*)(ws + OFF_HB);
  float* part_num = ws + OFF_PN;
  float* part_den = ws + OFF_PD;
  float* ctx = ws + OFF_CTX;

  detect_mask_kernel<<<dim3(1), dim3(256), 0, stream>>>(mask, mflag);

  constexpr int PTOT = Fdim * Hdim + (Mp - Fdim) * Kp / 2 + Wdim * Hdim +
                       (Np - Wdim) * Kp / 2 + Mp * NWRD + (Np / 32) * 64;
  prep2_kernel<<<dim3((PTOT + 255) / 256), dim3(256), 0, stream>>>(
      femb, hemb, Ww, bw, Wu, mask, mflag, A, B, mbits, hembB);

  score_ctx_kernel<<<dim3(Np / 128, Mp / 64), dim3(256), 0, stream>>>(
      A, B, mbits, hembB, part_num, part_den);

  finalize2_kernel<<<dim3((Fdim * Edim + 255) / 256), dim3(256), 0, stream>>>(
      part_num, part_den, ctx);

  out_gemv_kernel<<<dim3(Bdim), dim3(256), 0, stream>>>(values, ctx, out);
}

// Round 12
// 66.583 us; speedup vs baseline: 1.9107x; 1.0291x over previous
//
#include <hip/hip_runtime.h>

constexpr int Fdim = 2000;
constexpr int Wdim = 4000;
constexpr int Edim = 16;
constexpr int Hdim = 64;
constexpr int Bdim = 256;
constexpr float kLog2e = 1.4426950408889634f;

// ---- MFMA-path padded dims
constexpr int Mp = 2048;        // padded F
constexpr int Np = 4096;        // padded W
constexpr int Kp = 320;         // 5 tanh powers x 64 h
constexpr int NCHUNK = Np / 64; // 64 w-chunks of partials

typedef _Float16 f16x8 __attribute__((ext_vector_type(8)));
typedef _Float16 f16x2 __attribute__((ext_vector_type(2)));
typedef float f32x4 __attribute__((ext_vector_type(4)));

__device__ __forceinline__ float fast_exp2(float x) {
#if __has_builtin(__builtin_amdgcn_exp2f)
  return __builtin_amdgcn_exp2f(x);
#else
  return exp2f(x);
#endif
}
__device__ __forceinline__ float fast_rcp(float x) {
#if __has_builtin(__builtin_amdgcn_rcpf)
  return __builtin_amdgcn_rcpf(x);
#else
  return 1.0f / x;
#endif
}
__device__ __forceinline__ float dev_tanh(float x) {
  return 1.0f - 2.0f * fast_rcp(fast_exp2(2.0f * kLog2e * x) + 1.0f);
}
__device__ __forceinline__ f16x2 pack_f16(float a, float b) {
  return __builtin_bit_cast(f16x2, __builtin_amdgcn_cvt_pkrtz(a, b));
}

// ---- DPP wave-64 sum (VALU pipe). Result valid in lane 63.
template <int CTRL>
__device__ __forceinline__ float dpp_part(float x) {
  return __int_as_float(
      __builtin_amdgcn_update_dpp(0, __float_as_int(x), CTRL, 0xF, 0xF, true));
}
__device__ __forceinline__ float wave64_sum(float x) {
  const float x0 = x;
  x += dpp_part<0x111>(x0);
  x += dpp_part<0x112>(x0);
  x += dpp_part<0x113>(x0);
  x += dpp_part<0x114>(x);
  x += dpp_part<0x118>(x);
  x += dpp_part<0x142>(x);
  x += dpp_part<0x143>(x);
  return x;
}

// --- detect whether mask is 1-byte bool or 4-byte int32 -------------------
__global__ void detect_mask_kernel(const unsigned char* __restrict__ mask,
                                   int* __restrict__ flag) {
  __shared__ int any;
  if (threadIdx.x == 0) any = 0;
  __syncthreads();
  int acc = 0;
  for (int i = threadIdx.x; i < 8192; i += 256)
    if ((i & 3) != 0) acc |= mask[i];
  if (acc) atomicOr(&any, 1);
  __syncthreads();
  if (threadIdx.x == 0) *flag = (any != 0) ? 1 : 0;  // 1 = byte layout
}

// prep2: fp16 GEMM operands + hemb B-fragments (no mask work here).
//   A[f][j*64+h] = tanh(s)^j (j=0..4), s = femb@Ww[:E]; rows >=Fdim zeroed
//   B[w][j*64+h] = Wu[h]*{q,1-q^2,q^3-q,q^2-q^4,-q^3}, q=tanh(hid+b); pad 0
//   hembB[widx][lane][i] = hemb[widx*32+(lane>>4)*8+i][lane&15]  (fp16 frags)
__global__ __launch_bounds__(256) void prep2_kernel(
    const float* __restrict__ femb, const float* __restrict__ hemb,
    const float* __restrict__ Ww, const float* __restrict__ bw,
    const float* __restrict__ Wu, _Float16* __restrict__ A,
    _Float16* __restrict__ B, _Float16* __restrict__ hembB) {
  constexpr int PA = Fdim * Hdim;                  // 128000 A main
  constexpr int PAZ = PA + (Mp - Fdim) * Kp / 2;   // +7680 A pad (u32)
  constexpr int PB = PAZ + Wdim * Hdim;            // +256000 B main
  constexpr int PBZ = PB + (Np - Wdim) * Kp / 2;   // +15360 B pad (u32)
  constexpr int PH = PBZ + (Np / 32) * 64;         // +8192 hembB
  int idx = blockIdx.x * 256 + threadIdx.x;
  if (idx < PA) {
    int f = idx >> 6, h = idx & 63;
    float s = 0.f;
#pragma unroll
    for (int e = 0; e < Edim; ++e)
      s = fmaf(femb[f * Edim + e], Ww[e * Hdim + h], s);
    float p = dev_tanh(s);
    _Float16* a = A + (size_t)f * Kp + h;
    float pj = 1.0f;
#pragma unroll
    for (int j = 0; j < 5; ++j) {
      a[j * 64] = (_Float16)pj;
      pj *= p;
    }
  } else if (idx < PAZ) {
    ((unsigned int*)(A + (size_t)Fdim * Kp))[idx - PA] = 0u;
  } else if (idx < PB) {
    int jj = idx - PAZ;
    int w = jj >> 6, h = jj & 63;
    float t = bw[h];
#pragma unroll
    for (int e = 0; e < Edim; ++e)
      t = fmaf(hemb[w * Edim + e], Ww[(Edim + e) * Hdim + h], t);
    float q = dev_tanh(t);
    float wu = Wu[h];
    float q2 = q * q, q3 = q2 * q;
    _Float16* b = B + (size_t)w * Kp + h;
    b[0 * 64] = (_Float16)(wu * q);
    b[1 * 64] = (_Float16)(wu * (1.0f - q2));
    b[2 * 64] = (_Float16)(wu * (q3 - q));
    b[3 * 64] = (_Float16)(wu * (q2 - q2 * q2));
    b[4 * 64] = (_Float16)(-wu * q3);
  } else if (idx < PBZ) {
    ((unsigned int*)(B + (size_t)Wdim * Kp))[idx - PB] = 0u;
  } else if (idx < PH) {
    int j = idx - PBZ;
    int lane = j & 63;
    int e = lane & 15;
    int wb = (j >> 6) * 32 + (lane >> 4) * 8;
    f16x8 v;
#pragma unroll
    for (int i = 0; i < 8; ++i) {
      int w = wb + i;
      v[i] = (w < Wdim) ? (_Float16)hemb[(size_t)w * Edim + e] : (_Float16)0.f;
    }
    *(f16x8*)(hembB + (size_t)j * 8) = v;
  }
}

// score_ctx: fused, XCD-swizzled. Wave = 32f x 64w. First GEMM SWAPPED:
// mfma(B_w, A_f) -> D col=f (lane&15), row=w ((lane>>4)*4+r). Epilogue:
// exp2 * raw-mask (direct, each element read once), fp16 -> per-wave
// XOR-swizzled LDS tile [32f][64w]. Second GEMM: mfma(sc_lds, hembB)
// contracting w -> num[32f][16e]; den via in-reg sum + shfl_xor.
__global__ __launch_bounds__(256) void score_ctx_kernel(
    const _Float16* __restrict__ A, const _Float16* __restrict__ B,
    const unsigned char* __restrict__ mask_b, const int* __restrict__ mflag,
    const _Float16* __restrict__ hembB,
    float* __restrict__ part_num, float* __restrict__ part_den) {
  __shared__ __align__(16) char smem[16384];  // 4 KB per wave
  const int tid = threadIdx.x;
  const int wid = tid >> 6, lane = tid & 63;
  const int wr = wid >> 1, wc = wid & 1;

  // ---- bijective XCD swizzle (1024 blocks, 8 XCDs): XCD c gets 4
  // consecutive w-tiles x all 32 f-tiles -> per-XCD L2 set ~1.6 MB.
  const int lin = blockIdx.y * 32 + blockIdx.x;
  const int nl = (lin & 7) * 128 + (lin >> 3);
  const int bx = nl >> 5;   // w-tile index [0,32)
  const int by = nl & 31;   // f-tile index [0,32)

  const int fbase = by * 64 + wr * 32;
  const int wbase = bx * 128 + wc * 64;
  const int lrow = lane & 15, g = lane >> 4;

  f32x4 accT[4][2];  // [mw (w-frag)][nf (f-frag)]
#pragma unroll
  for (int mw = 0; mw < 4; ++mw)
#pragma unroll
    for (int nf = 0; nf < 2; ++nf) accT[mw][nf] = (f32x4){0.f, 0.f, 0.f, 0.f};

  const _Float16* Bw = B + (size_t)(wbase + lrow) * Kp + g * 8;
  const _Float16* Af = A + (size_t)(fbase + lrow) * Kp + g * 8;
#pragma unroll 2
  for (int ks = 0; ks < Kp / 32; ++ks) {
    f16x8 bw[4], af[2];
#pragma unroll
    for (int mw = 0; mw < 4; ++mw)
      bw[mw] = *(const f16x8*)(Bw + (size_t)mw * 16 * Kp + ks * 32);
#pragma unroll
    for (int nf = 0; nf < 2; ++nf)
      af[nf] = *(const f16x8*)(Af + (size_t)nf * 16 * Kp + ks * 32);
#pragma unroll
    for (int mw = 0; mw < 4; ++mw)
#pragma unroll
      for (int nf = 0; nf < 2; ++nf)
        accT[mw][nf] = __builtin_amdgcn_mfma_f32_16x16x32_f16(
            bw[mw], af[nf], accT[mw][nf], 0, 0, 0);
  }

  // ---- epilogue: exp2 * mask -> fp16 -> swizzled LDS; den partials.
  // Direct mask read: lane needs w = wbase + mw*16 + g*4 + r (r=0..3) for
  // its 2 f's -> one dword (byte layout) or dwordx4 (int layout) per (nf,mw).
  const int mbyte = *mflag;  // uniform
  const int* mask_i = (const int*)mask_b;
  char* sbase = smem + wid * 4096;
  float denp[2] = {0.f, 0.f};
#pragma unroll
  for (int nf = 0; nf < 2; ++nf) {
    const int f = fbase + nf * 16 + lrow;
    const bool fok = (f < Fdim);
    const int fl = nf * 16 + lrow;
    const int sw = (fl & 7) << 4;
#pragma unroll
    for (int mw = 0; mw < 4; ++mw) {
      const int w0 = wbase + mw * 16 + g * 4;      // Wdim%16==0 -> uniform ok
      const bool wok = (w0 < Wdim);
      float mm[4];
      if (mbyte) {
        unsigned int md =
            (fok && wok) ? *(const unsigned int*)(mask_b + (size_t)f * Wdim + w0)
                         : 0u;
#pragma unroll
        for (int r = 0; r < 4; ++r)
          mm[r] = (float)(((md >> (8 * r)) & 0xFFu) ? 1 : 0);
      } else {
        uint4 mi = (fok && wok)
                       ? *(const uint4*)(mask_i + (size_t)f * Wdim + w0)
                       : make_uint4(0u, 0u, 0u, 0u);
        mm[0] = mi.x ? 1.f : 0.f;
        mm[1] = mi.y ? 1.f : 0.f;
        mm[2] = mi.z ? 1.f : 0.f;
        mm[3] = mi.w ? 1.f : 0.f;
      }
      float v[4];
#pragma unroll
      for (int r = 0; r < 4; ++r) {
        v[r] = fast_exp2(accT[mw][nf][r] * kLog2e) * mm[r];
        denp[nf] += v[r];
      }
      const int wb0 = (mw * 16 + g * 4) * 2;
      *(f16x2*)(sbase + fl * 128 + ((wb0 + 0) ^ sw)) = pack_f16(v[0], v[1]);
      *(f16x2*)(sbase + fl * 128 + ((wb0 + 4) ^ sw)) = pack_f16(v[2], v[3]);
    }
  }

  // ---- second GEMM: num[32f][16e] over this wave's 64 w
  f32x4 numT[2];
#pragma unroll
  for (int nf = 0; nf < 2; ++nf) numT[nf] = (f32x4){0.f, 0.f, 0.f, 0.f};
#pragma unroll
  for (int kstep = 0; kstep < 2; ++kstep) {
    const f16x8 hb = *(const f16x8*)(
        hembB + ((size_t)(wbase >> 5) + kstep) * 512 + lane * 8);
#pragma unroll
    for (int nf = 0; nf < 2; ++nf) {
      const int fl = nf * 16 + lrow;
      const f16x8 scf = *(const f16x8*)(
          sbase + fl * 128 + ((kstep * 64 + g * 16) ^ ((fl & 7) << 4)));
      numT[nf] = __builtin_amdgcn_mfma_f32_16x16x32_f16(scf, hb, numT[nf],
                                                        0, 0, 0);
    }
  }

  // ---- den: sum across the 4 lane-groups (same f, different g)
#pragma unroll
  for (int nf = 0; nf < 2; ++nf) {
    float d = denp[nf];
    d += __shfl_xor(d, 16, 64);
    d += __shfl_xor(d, 32, 64);
    denp[nf] = d;
  }

  // ---- write partials for this (64-w chunk)
  const int chunk = bx * 2 + wc;
  if (lane < 16) {
#pragma unroll
    for (int nf = 0; nf < 2; ++nf)
      part_den[(size_t)chunk * Mp + fbase + nf * 16 + lrow] = denp[nf];
  }
#pragma unroll
  for (int nf = 0; nf < 2; ++nf)
#pragma unroll
    for (int r = 0; r < 4; ++r) {
      const int f = fbase + nf * 16 + g * 4 + r;
      part_num[((size_t)chunk * Mp + f) * Edim + lrow] = numT[nf][r];
    }
}

// finalize: ctx[f][e] = sum_c num / sum_c den
__global__ __launch_bounds__(256) void finalize2_kernel(
    const float* __restrict__ part_num, const float* __restrict__ part_den,
    float* __restrict__ ctx) {
  int idx = blockIdx.x * 256 + threadIdx.x;
  if (idx >= Fdim * Edim) return;
  int f = idx >> 4, e = idx & 15;
  float num = 0.f, den = 0.f;
#pragma unroll 4
  for (int c = 0; c < NCHUNK; ++c) {
    num += part_num[((size_t)c * Mp + f) * Edim + e];
    den += part_den[(size_t)c * Mp + f];
  }
  ctx[idx] = num / den;
}

// out[b][e] = sum_f values[b][f] * ctx[f][e]
__global__ __launch_bounds__(256) void out_gemv_kernel(
    const float* __restrict__ values, const float* __restrict__ ctx,
    float* __restrict__ out) {
  const int b = blockIdx.x, tid = threadIdx.x;
  float acc[Edim];
#pragma unroll
  for (int e = 0; e < Edim; ++e) acc[e] = 0.f;
  for (int f = tid; f < Fdim; f += 256) {
    float v = values[b * Fdim + f];
    const float4* c4 = (const float4*)(ctx + f * Edim);
    float4 c0 = c4[0], c1 = c4[1], c2 = c4[2], c3 = c4[3];
    float cr[Edim] = {c0.x, c0.y, c0.z, c0.w, c1.x, c1.y, c1.z, c1.w,
                      c2.x, c2.y, c2.z, c2.w, c3.x, c3.y, c3.z, c3.w};
#pragma unroll
    for (int e = 0; e < Edim; ++e) acc[e] = fmaf(v, cr[e], acc[e]);
  }
  __shared__ float s_red[4][Edim];
  const int lane = tid & 63, wv = tid >> 6;
#pragma unroll
  for (int e = 0; e < Edim; ++e) {
    float a = wave64_sum(acc[e]);
    if (lane == 63) s_red[wv][e] = a;
  }
  __syncthreads();
  if (tid < Edim)
    out[b * Edim + tid] =
        s_red[0][tid] + s_red[1][tid] + s_red[2][tid] + s_red[3][tid];
}

extern "C" void kernel_launch(void* const* d_in, const int* in_sizes, int n_in,
                              void* d_out, int out_size, void* d_ws,
                              size_t ws_size, hipStream_t stream) {
  const float* values = (const float*)d_in[0];
  const float* femb   = (const float*)d_in[1];
  const float* hemb   = (const float*)d_in[2];
  const float* Ww     = (const float*)d_in[3];
  const float* bw     = (const float*)d_in[4];
  const float* Wu     = (const float*)d_in[5];
  const unsigned char* mask = (const unsigned char*)d_in[6];
  float* out = (float*)d_out;
  float* ws = (float*)d_ws;

  // ws layout (float units). Total ~13 MB.
  const size_t OFF_FLG = 0;                                  // 16
  const size_t OFF_A = 16;                                   // Mp*Kp/2 = 327680
  const size_t OFF_B = OFF_A + (size_t)Mp * Kp / 2;          // Np*Kp/2 = 655360
  const size_t OFF_HB = OFF_B + (size_t)Np * Kp / 2;         // 32768
  const size_t OFF_PN = OFF_HB + 32768;                      // 64*2048*16 = 2097152
  const size_t OFF_PD = OFF_PN + (size_t)NCHUNK * Mp * Edim; // 131072
  const size_t OFF_CTX = OFF_PD + (size_t)NCHUNK * Mp;       // 32000

  int* mflag = (int*)(ws + OFF_FLG);
  _Float16* A = (_Float16*)(ws + OFF_A);
  _Float16* B = (_Float16*)(ws + OFF_B);
  _Float16* hembB = (_Float16*)(ws + OFF_HB);
  float* part_num = ws + OFF_PN;
  float* part_den = ws + OFF_PD;
  float* ctx = ws + OFF_CTX;

  detect_mask_kernel<<<dim3(1), dim3(256), 0, stream>>>(mask, mflag);

  constexpr int PTOT = Fdim * Hdim + (Mp - Fdim) * Kp / 2 + Wdim * Hdim +
                       (Np - Wdim) * Kp / 2 + (Np / 32) * 64;  // 415232
  prep2_kernel<<<dim3((PTOT + 255) / 256), dim3(256), 0, stream>>>(
      femb, hemb, Ww, bw, Wu, A, B, hembB);

  score_ctx_kernel<<<dim3(Np / 128, Mp / 64), dim3(256), 0, stream>>>(
      A, B, mask, mflag, hembB, part_num, part_den);

  finalize2_kernel<<<dim3((Fdim * Edim + 255) / 256), dim3(256), 0, stream>>>(
      part_num, part_den, ctx);

  out_gemv_kernel<<<dim3(Bdim), dim3(256), 0, stream>>>(values, ctx, out);
}